// Round 2
// baseline (600.394 us; speedup 1.0000x reference)
//
#include <hip/hip_runtime.h>
#include <hip/hip_fp16.h>

#define EPSV 1e-5f
#define BIN_CH 4096
#define BCAP 8192   // fixed bucket capacity (mean ~4348, sigma ~66 for uniform random)

typedef _Float16 f16;
typedef f16 half8 __attribute__((ext_vector_type(8)));
typedef float f32x4 __attribute__((ext_vector_type(4)));

// ---------------- binned CSR construction (single-pass, fixed-capacity buckets) ----

__global__ __launch_bounds__(256) void k_bin(const int* __restrict__ src,
                                             const int* __restrict__ dst, int E, int EN,
                                             int NBK, int* __restrict__ gcur,
                                             int* __restrict__ binned) {
    __shared__ int cnt[512];
    __shared__ int base[512];
    for (int b = threadIdx.x; b < 512; b += 256) cnt[b] = 0;
    __syncthreads();
    int i0 = blockIdx.x * BIN_CH;
    int i1 = i0 + BIN_CH; if (i1 > EN) i1 = EN;
    for (int i = i0 + threadIdx.x; i < i1; i += 256) {
        int d = (i < E) ? dst[i] : (i - E);
        atomicAdd(&cnt[d >> 8], 1);
    }
    __syncthreads();
    for (int b = threadIdx.x; b < NBK; b += 256)
        if (cnt[b]) base[b] = b * BCAP + atomicAdd(&gcur[b], cnt[b]);
    __syncthreads();
    for (int i = i0 + threadIdx.x; i < i1; i += 256) {
        int s, d;
        if (i < E) { s = src[i]; d = dst[i]; }
        else       { s = i - E; d = s; }
        int pos = atomicAdd(&base[d >> 8], 1);
        binned[pos] = s | ((d & 255) << 24);   // src < 2^24
    }
}

__global__ __launch_bounds__(256) void k_bucket(const int* __restrict__ binned,
                                                const int* __restrict__ gcur, int N,
                                                int* __restrict__ deg, int* __restrict__ rs,
                                                int* __restrict__ csr_s,
                                                float* __restrict__ disq) {
    __shared__ int deg_l[256];
    __shared__ int sc[256];
    __shared__ int cur_l[256];
    int b = blockIdx.x;
    int t = threadIdx.x;
    int start = b * BCAP, end = start + gcur[b];
    deg_l[t] = 0;
    __syncthreads();
    for (int i = start + t; i < end; i += 256)
        atomicAdd(&deg_l[((unsigned)binned[i]) >> 24], 1);
    __syncthreads();
    sc[t] = deg_l[t];
    __syncthreads();
    for (int off = 1; off < 256; off <<= 1) {
        int v = (t >= off) ? sc[t - off] : 0;
        __syncthreads();
        sc[t] += v;
        __syncthreads();
    }
    int rs_l = sc[t] - deg_l[t];
    int n = b * 256 + t;
    if (n < N) {
        deg[n] = deg_l[t];
        rs[n] = start + rs_l;
        disq[n] = rsqrtf((float)(deg_l[t] > 0 ? deg_l[t] : 1));
    }
    cur_l[t] = start + rs_l;
    __syncthreads();
    for (int i = start + t; i < end; i += 256) {
        int p = binned[i];
        int loc = ((unsigned)p) >> 24;
        int idx = atomicAdd(&cur_l[loc], 1);
        csr_s[idx] = p & 0xFFFFFF;
    }
}

__global__ __launch_bounds__(256) void k_wfill(const int* __restrict__ rs,
                                               const int* __restrict__ deg,
                                               const int* __restrict__ csr_s,
                                               const float* __restrict__ disq,
                                               float* __restrict__ csr_w, int N) {
    int wave = threadIdx.x >> 6, lane = threadIdx.x & 63;
    int n = blockIdx.x * 4 + wave;
    if (n >= N) return;
    int e0 = rs[n], dg = deg[n];
    float dn = disq[n];
    for (int j = lane; j < dg; j += 64) {
        int s = csr_s[e0 + j];
        csr_w[e0 + j] = disq[s] * dn;
    }
}

// ---- fused per-layer prep: scale/shift from raw sums + Wp_t + wrow ----

__global__ __launch_bounds__(256) void k_prep(
    const float* __restrict__ colsum, const float* __restrict__ colsq,
    const float* __restrict__ g, const float* __restrict__ b, float invN,
    const float* __restrict__ W, int Cin, int Cout, int KP,
    f16* __restrict__ Wp, float* __restrict__ wrow) {
    __shared__ float lsc[192];
    __shared__ float lsh[192];
    __shared__ float red[4];
    int t = threadIdx.x;
    int c = blockIdx.x;
    if (t < KP) {
        float scv = 0.f, shv = 0.f;
        if (t < Cin) {
            float m = colsum[t] * invN;
            float v = colsq[t] * invN - m * m;
            float rstd = rsqrtf(fmaxf(v, 0.f) + EPSV);
            scv = rstd * g[t];
            shv = b[t] - m * scv;
        }
        lsc[t] = scv; lsh[t] = shv;
    }
    __syncthreads();
    float part = 0.f;
    if (t < KP) {
        float wv = (t < Cin && c < Cout) ? W[(size_t)t * Cout + c] : 0.f;
        Wp[(size_t)c * KP + t] = (f16)(lsc[t] * wv);
        part = lsh[t] * wv;
    }
    for (int off = 32; off > 0; off >>= 1) part += __shfl_down(part, off);
    int lane = t & 63, wid = t >> 6;
    if (lane == 0) red[wid] = part;
    __syncthreads();
    if (t == 0) wrow[c] = red[0] + red[1] + red[2] + red[3];
}

// -- pad x [N,7] -> xp [N,8] fp16 + BN stats (direct atomics) + graph bounds --

__global__ __launch_bounds__(256) void k_padx_stats(const float* __restrict__ x,
                                                    __half* __restrict__ xp, int N,
                                                    float* __restrict__ colsum,
                                                    float* __restrict__ colsq,
                                                    const int* __restrict__ batch,
                                                    int* __restrict__ gstart,
                                                    int* __restrict__ gend) {
    __shared__ float ls[16];
    int t = threadIdx.x;
    int n = blockIdx.x * 256 + t;
    int lane = t & 63;
    if (t < 16) ls[t] = 0.f;
    __syncthreads();
    float v[7] = {0.f, 0.f, 0.f, 0.f, 0.f, 0.f, 0.f};
    if (n < N) {
#pragma unroll
        for (int j = 0; j < 7; ++j) v[j] = x[(size_t)n * 7 + j];
        __half h[8];
#pragma unroll
        for (int j = 0; j < 7; ++j) h[j] = __float2half(v[j]);
        h[7] = __float2half(0.f);
        *(float4*)(xp + (size_t)n * 8) = *(float4*)h;
        // graph segment bounds (batch sorted)
        int g = batch[n];
        int gp = (n == 0) ? -1 : batch[n - 1];
        if (gp != g) gstart[g] = n;
        int gn = (n == N - 1) ? -1 : batch[n + 1];
        if (gn != g) gend[g] = n + 1;
    }
#pragma unroll
    for (int j = 0; j < 7; ++j) {
        float s = v[j];
        float q = v[j] * v[j];
        for (int off = 32; off > 0; off >>= 1) {
            s += __shfl_down(s, off);
            q += __shfl_down(q, off);
        }
        if (lane == 0) {
            atomicAdd(&ls[j], s);
            atomicAdd(&ls[8 + j], q);
        }
    }
    __syncthreads();
    if (t < 8)               atomicAdd(&colsum[t], ls[t]);
    else if (t < 16)         atomicAdd(&colsq[t - 8], ls[t]);
}

// ---------------- gathers: G = S . X ----------------

// layer-1 gather: fp16 xp table (16B rows, 1.6MB -> L2-resident), also emits rsum
__global__ void k_gather8(const __half* __restrict__ xp, const int* __restrict__ csr_s,
                          const float* __restrict__ csr_w,
                          const int* __restrict__ rs, const int* __restrict__ deg,
                          __half* __restrict__ out, float* __restrict__ rsum, int N) {
    int n = blockIdx.x * blockDim.x + threadIdx.x;
    if (n >= N) return;
    int e0 = rs[n], eend = e0 + deg[n];
    float a0 = 0.f, a1 = 0.f, a2 = 0.f, a3 = 0.f, a4 = 0.f, a5 = 0.f, a6 = 0.f, a7 = 0.f;
    float ws = 0.f;
    for (int e = e0; e < eend; ++e) {
        int s = csr_s[e];
        float w = csr_w[e];
        ws += w;
        float4 r = *(const float4*)(xp + (size_t)s * 8);
        const __half2* hh = (const __half2*)&r;
        float2 q0 = __half22float2(hh[0]);
        float2 q1 = __half22float2(hh[1]);
        float2 q2 = __half22float2(hh[2]);
        float2 q3 = __half22float2(hh[3]);
        a0 = fmaf(w, q0.x, a0); a1 = fmaf(w, q0.y, a1);
        a2 = fmaf(w, q1.x, a2); a3 = fmaf(w, q1.y, a3);
        a4 = fmaf(w, q2.x, a4); a5 = fmaf(w, q2.y, a5);
        a6 = fmaf(w, q3.x, a6); a7 = fmaf(w, q3.y, a7);
    }
    rsum[n] = ws;
    __half h[8];
    h[0] = __float2half(a0); h[1] = __float2half(a1);
    h[2] = __float2half(a2); h[3] = __float2half(a3);
    h[4] = __float2half(a4); h[5] = __float2half(a5);
    h[6] = __float2half(a6); h[7] = __float2half(a7);
    *(float4*)(out + (size_t)n * 8) = *(float4*)h;
}

// tail gather: 8-half rows from small L2-resident table -> out cols [coff, coff+8)
__global__ __launch_bounds__(256) void k_gather_tail(
    const __half* __restrict__ At, const int* __restrict__ csr_s,
    const float* __restrict__ csr_w, const int* __restrict__ rs,
    const int* __restrict__ deg, __half* __restrict__ out, int SPo, int coff, int N) {
    int n = blockIdx.x * blockDim.x + threadIdx.x;
    if (n >= N) return;
    int e0 = rs[n], eend = e0 + deg[n];
    float a0 = 0.f, a1 = 0.f, a2 = 0.f, a3 = 0.f, a4 = 0.f, a5 = 0.f, a6 = 0.f, a7 = 0.f;
    for (int e = e0; e < eend; ++e) {
        int s = csr_s[e];
        float w = csr_w[e];
        float4 r = *(const float4*)(At + (size_t)s * 8);
        const __half2* hh = (const __half2*)&r;
        float2 q0 = __half22float2(hh[0]);
        float2 q1 = __half22float2(hh[1]);
        float2 q2 = __half22float2(hh[2]);
        float2 q3 = __half22float2(hh[3]);
        a0 = fmaf(w, q0.x, a0); a1 = fmaf(w, q0.y, a1);
        a2 = fmaf(w, q1.x, a2); a3 = fmaf(w, q1.y, a3);
        a4 = fmaf(w, q2.x, a4); a5 = fmaf(w, q2.y, a5);
        a6 = fmaf(w, q3.x, a6); a7 = fmaf(w, q3.y, a7);
    }
    __half2 h[4];
    h[0] = __floats2half2_rn(a0, a1);
    h[1] = __floats2half2_rn(a2, a3);
    h[2] = __floats2half2_rn(a4, a5);
    h[3] = __floats2half2_rn(a6, a7);
    *(float4*)(out + (size_t)n * SPo + coff) = *(float4*)h;
}

// multi-node-per-wave MAIN gather (power-of-2 chunks, all 64 lanes active):
//   Am rows of SPm halfs (128B-aligned); CH8 = SPm/8 chunks; SH = log2(CH8).
__global__ __launch_bounds__(256) void k_gather_w(
    const __half* __restrict__ Am, int SPm, int SH,
    const int* __restrict__ rs, const int* __restrict__ deg,
    const int* __restrict__ csr_s, const float* __restrict__ csr_w,
    __half* __restrict__ out, int SPo, int N) {
    int wave = threadIdx.x >> 6;
    int lane = threadIdx.x & 63;
    int sub = lane >> SH;
    int lsub = lane & ((1 << SH) - 1);
    int npw = 64 >> SH;
    int n = (blockIdx.x * 4 + wave) * npw + sub;
    bool active = (n < N);
    int e0 = 0, eend = 0;
    if (active) { e0 = rs[n]; eend = e0 + deg[n]; }
    const __half* base = Am + lsub * 8;
    float acc[8] = {};

    int e = e0;
    for (; e + 8 <= eend; e += 8) {
        int s[8]; float wv[8]; float4 r[8];
#pragma unroll
        for (int i = 0; i < 8; ++i) { s[i] = csr_s[e + i]; wv[i] = csr_w[e + i]; }
#pragma unroll
        for (int i = 0; i < 8; ++i) r[i] = *(const float4*)(base + (size_t)s[i] * SPm);
#pragma unroll
        for (int i = 0; i < 8; ++i) {
            float2 q0 = __half22float2(((const __half2*)&r[i])[0]);
            float2 q1 = __half22float2(((const __half2*)&r[i])[1]);
            float2 q2 = __half22float2(((const __half2*)&r[i])[2]);
            float2 q3 = __half22float2(((const __half2*)&r[i])[3]);
            acc[0] = fmaf(wv[i], q0.x, acc[0]); acc[1] = fmaf(wv[i], q0.y, acc[1]);
            acc[2] = fmaf(wv[i], q1.x, acc[2]); acc[3] = fmaf(wv[i], q1.y, acc[3]);
            acc[4] = fmaf(wv[i], q2.x, acc[4]); acc[5] = fmaf(wv[i], q2.y, acc[5]);
            acc[6] = fmaf(wv[i], q3.x, acc[6]); acc[7] = fmaf(wv[i], q3.y, acc[7]);
        }
    }
    for (; e + 4 <= eend; e += 4) {
        int s[4]; float wv[4]; float4 r[4];
#pragma unroll
        for (int i = 0; i < 4; ++i) { s[i] = csr_s[e + i]; wv[i] = csr_w[e + i]; }
#pragma unroll
        for (int i = 0; i < 4; ++i) r[i] = *(const float4*)(base + (size_t)s[i] * SPm);
#pragma unroll
        for (int i = 0; i < 4; ++i) {
            float2 q0 = __half22float2(((const __half2*)&r[i])[0]);
            float2 q1 = __half22float2(((const __half2*)&r[i])[1]);
            float2 q2 = __half22float2(((const __half2*)&r[i])[2]);
            float2 q3 = __half22float2(((const __half2*)&r[i])[3]);
            acc[0] = fmaf(wv[i], q0.x, acc[0]); acc[1] = fmaf(wv[i], q0.y, acc[1]);
            acc[2] = fmaf(wv[i], q1.x, acc[2]); acc[3] = fmaf(wv[i], q1.y, acc[3]);
            acc[4] = fmaf(wv[i], q2.x, acc[4]); acc[5] = fmaf(wv[i], q2.y, acc[5]);
            acc[6] = fmaf(wv[i], q3.x, acc[6]); acc[7] = fmaf(wv[i], q3.y, acc[7]);
        }
    }
    for (; e < eend; ++e) {
        int s = csr_s[e];
        float w = csr_w[e];
        float4 r = *(const float4*)(base + (size_t)s * SPm);
        float2 q0 = __half22float2(((const __half2*)&r)[0]);
        float2 q1 = __half22float2(((const __half2*)&r)[1]);
        float2 q2 = __half22float2(((const __half2*)&r)[2]);
        float2 q3 = __half22float2(((const __half2*)&r)[3]);
        acc[0] = fmaf(w, q0.x, acc[0]); acc[1] = fmaf(w, q0.y, acc[1]);
        acc[2] = fmaf(w, q1.x, acc[2]); acc[3] = fmaf(w, q1.y, acc[3]);
        acc[4] = fmaf(w, q2.x, acc[4]); acc[5] = fmaf(w, q2.y, acc[5]);
        acc[6] = fmaf(w, q3.x, acc[6]); acc[7] = fmaf(w, q3.y, acc[7]);
    }

    if (active) {
        __half2 h[4];
        h[0] = __floats2half2_rn(acc[0], acc[1]);
        h[1] = __floats2half2_rn(acc[2], acc[3]);
        h[2] = __floats2half2_rn(acc[4], acc[5]);
        h[3] = __floats2half2_rn(acc[6], acc[7]);
        *(float4*)(out + (size_t)n * SPo + lsub * 8) = *(float4*)h;
    }
}

// ------------- MFMA GEMM: H = relu(G @ Wp_t^T + rsum (x) wrow + bias) -------------
// Output routed to split tables: cols [0,MAIN) -> outM (stride SPm), [MAIN,TOTW) -> outT (stride 8).

__global__ __launch_bounds__(256) void k_gemm_mfma(
    const f16* __restrict__ A, int SPa,
    const f16* __restrict__ Bt, int KP,
    const float* __restrict__ rsum, const float* __restrict__ wrow,
    const float* __restrict__ bias,
    f16* __restrict__ outM, int SPm, int MAIN, f16* __restrict__ outT, int TOTW,
    float* __restrict__ colsum, float* __restrict__ colsq, int do_stats,
    int N, int Cout) {
    __shared__ f16 As[128][40];
    __shared__ float s_sum[64];
    __shared__ float s_sq[64];
    const int r0 = blockIdx.x * 128;
    const int c0 = blockIdx.y * 64;
    const int t = threadIdx.x;
    const int wave = t >> 6, lane = t & 63;
    const int l15 = lane & 15, quad = lane >> 4;

    if (t < 64) { s_sum[t] = 0.f; s_sq[t] = 0.f; }

    f32x4 zero4 = {0.f, 0.f, 0.f, 0.f};
    f32x4 acc[2][4];
#pragma unroll
    for (int mi = 0; mi < 2; ++mi)
#pragma unroll
        for (int ni = 0; ni < 4; ++ni) acc[mi][ni] = zero4;

    const int KT = KP >> 5;
    for (int kt = 0; kt < KT; ++kt) {
        int k0 = kt * 32;
        {
            int kcol = (t & 7) * 4;
            int rbase = t >> 3;
            int gk = k0 + kcol;
            bool kok = (gk + 4 <= SPa);
#pragma unroll
            for (int i = 0; i < 4; ++i) {
                int row = rbase + i * 32;
                int gr = r0 + row;
                ushort4 v = {0, 0, 0, 0};
                if (gr < N && kok)
                    v = *(const ushort4*)(A + (size_t)gr * SPa + gk);
                *(ushort4*)&As[row][kcol] = v;
            }
        }
        __syncthreads();
        half8 a0 = *(const half8*)&As[wave * 32 + l15][quad * 8];
        half8 a1 = *(const half8*)&As[wave * 32 + 16 + l15][quad * 8];
#pragma unroll
        for (int ni = 0; ni < 4; ++ni) {
            half8 b = *(const half8*)(Bt + (size_t)(c0 + ni * 16 + l15) * KP + k0 + quad * 8);
            acc[0][ni] = __builtin_amdgcn_mfma_f32_16x16x32_f16(a0, b, acc[0][ni], 0, 0, 0);
            acc[1][ni] = __builtin_amdgcn_mfma_f32_16x16x32_f16(a1, b, acc[1][ni], 0, 0, 0);
        }
        __syncthreads();
    }

    float wr[4], bi[4];
#pragma unroll
    for (int ni = 0; ni < 4; ++ni) {
        int gc = c0 + ni * 16 + l15;
        wr[ni] = wrow[gc];
        bi[ni] = (gc < Cout) ? bias[gc] : 0.f;
    }
    float ps[4] = {}, pq[4] = {};
#pragma unroll
    for (int mi = 0; mi < 2; ++mi) {
#pragma unroll
        for (int reg = 0; reg < 4; ++reg) {
            int gr = r0 + wave * 32 + mi * 16 + quad * 4 + reg;
            if (gr >= N) continue;
            float rsv = rsum[gr];
#pragma unroll
            for (int ni = 0; ni < 4; ++ni) {
                int gc = c0 + ni * 16 + l15;
                float o = acc[mi][ni][reg] + rsv * wr[ni] + bi[ni];
                o = fmaxf(o, 0.f);
                if (gc >= Cout) o = 0.f;
                ps[ni] += o; pq[ni] += o * o;
                if (gc < MAIN) {
                    if (gc < TOTW) outM[(size_t)gr * SPm + gc] = (f16)o;
                } else if (gc < TOTW) {
                    outT[(size_t)gr * 8 + (gc - MAIN)] = (f16)o;
                }
            }
        }
    }
    if (do_stats) {
#pragma unroll
        for (int ni = 0; ni < 4; ++ni) {
            int cl = ni * 16 + l15;
            atomicAdd(&s_sum[cl], ps[ni]);
            atomicAdd(&s_sq[cl], pq[ni]);
        }
        __syncthreads();
        if (t < 64 && c0 + t < Cout) {
            atomicAdd(&colsum[c0 + t], s_sum[t]);
            atomicAdd(&colsq[c0 + t], s_sq[t]);
        }
    }
}

// ---- layer-3 GEMM with fused mean-pool accumulation (no H3 materialization) ----

__global__ __launch_bounds__(256) void k_gemm_pool(
    const f16* __restrict__ A, int SPa,
    const f16* __restrict__ Bt, int KP,
    const float* __restrict__ rsum, const float* __restrict__ wrow,
    const float* __restrict__ bias, const int* __restrict__ batch,
    float* __restrict__ pooled, int N, int Cout) {
    __shared__ f16 As[128][40];
    __shared__ int sbat[128];
    __shared__ float s_pool[16][64];
    const int r0 = blockIdx.x * 128;
    const int c0 = blockIdx.y * 64;
    const int t = threadIdx.x;
    const int wave = t >> 6, lane = t & 63;
    const int l15 = lane & 15, quad = lane >> 4;

    if (t < 128) {
        int gr = r0 + t;
        sbat[t] = batch[(gr < N) ? gr : (N - 1)];
    }
    for (int i = t; i < 16 * 64; i += 256) ((float*)s_pool)[i] = 0.f;

    f32x4 zero4 = {0.f, 0.f, 0.f, 0.f};
    f32x4 acc[2][4];
#pragma unroll
    for (int mi = 0; mi < 2; ++mi)
#pragma unroll
        for (int ni = 0; ni < 4; ++ni) acc[mi][ni] = zero4;

    const int KT = KP >> 5;
    for (int kt = 0; kt < KT; ++kt) {
        int k0 = kt * 32;
        {
            int kcol = (t & 7) * 4;
            int rbase = t >> 3;
            int gk = k0 + kcol;
            bool kok = (gk + 4 <= SPa);
#pragma unroll
            for (int i = 0; i < 4; ++i) {
                int row = rbase + i * 32;
                int gr = r0 + row;
                ushort4 v = {0, 0, 0, 0};
                if (gr < N && kok)
                    v = *(const ushort4*)(A + (size_t)gr * SPa + gk);
                *(ushort4*)&As[row][kcol] = v;
            }
        }
        __syncthreads();
        half8 a0 = *(const half8*)&As[wave * 32 + l15][quad * 8];
        half8 a1 = *(const half8*)&As[wave * 32 + 16 + l15][quad * 8];
#pragma unroll
        for (int ni = 0; ni < 4; ++ni) {
            half8 b = *(const half8*)(Bt + (size_t)(c0 + ni * 16 + l15) * KP + k0 + quad * 8);
            acc[0][ni] = __builtin_amdgcn_mfma_f32_16x16x32_f16(a0, b, acc[0][ni], 0, 0, 0);
            acc[1][ni] = __builtin_amdgcn_mfma_f32_16x16x32_f16(a1, b, acc[1][ni], 0, 0, 0);
        }
        __syncthreads();
    }

    const int g0 = sbat[0];
    const int gmax = sbat[127];
    float wr[4], bi[4];
#pragma unroll
    for (int ni = 0; ni < 4; ++ni) {
        int gc = c0 + ni * 16 + l15;
        wr[ni] = wrow[gc];
        bi[ni] = (gc < Cout) ? bias[gc] : 0.f;
    }
#pragma unroll
    for (int mi = 0; mi < 2; ++mi) {
#pragma unroll
        for (int reg = 0; reg < 4; ++reg) {
            int lrow = wave * 32 + mi * 16 + quad * 4 + reg;
            int gr = r0 + lrow;
            if (gr >= N) continue;
            float rsv = rsum[gr];
            int slot = sbat[lrow] - g0;
#pragma unroll
            for (int ni = 0; ni < 4; ++ni) {
                int gc = c0 + ni * 16 + l15;
                if (gc >= Cout) continue;
                float o = acc[mi][ni][reg] + rsv * wr[ni] + bi[ni];
                o = fmaxf(o, 0.f);
                if (slot < 16) atomicAdd(&s_pool[slot][ni * 16 + l15], o);
                else           atomicAdd(&pooled[(size_t)(g0 + slot) * Cout + gc], o);
            }
        }
    }
    __syncthreads();
    {
        int cl = t & 63, sl = t >> 6;
        int gc = c0 + cl;
        if (gc < Cout) {
            for (int slot = sl; slot < 16; slot += 4) {
                int g = g0 + slot;
                if (g > gmax) break;
                float v = s_pool[slot][cl];
                if (v != 0.f) atomicAdd(&pooled[(size_t)g * Cout + gc], v);
            }
        }
    }
}

// ---------------- head MLP ----------------

__global__ void k_mlp(const float* __restrict__ pooled, const int* __restrict__ gstart,
                      const int* __restrict__ gend,
                      const float* __restrict__ Wl1, const float* __restrict__ bl1,
                      const float* __restrict__ Wl2, const float* __restrict__ bl2,
                      float* __restrict__ out, int C) {
    __shared__ float p[199];
    __shared__ float t1[49];
    int g = blockIdx.x;
    int cnt = gend[g] - gstart[g];
    float inv = 1.f / (float)(cnt > 1 ? cnt : 1);
    for (int k = threadIdx.x; k < C; k += blockDim.x) p[k] = pooled[g * C + k] * inv;
    __syncthreads();
    if (threadIdx.x < 49) {
        float acc = bl1[threadIdx.x];
        for (int k = 0; k < C; ++k) acc += p[k] * Wl1[k * 49 + threadIdx.x];
        t1[threadIdx.x] = acc;
    }
    __syncthreads();
    if (threadIdx.x < 2) {
        float acc = bl2[threadIdx.x];
        for (int k = 0; k < 49; ++k) acc += t1[k] * Wl2[k * 2 + threadIdx.x];
        out[g * 2 + threadIdx.x] = acc;
    }
}

// ---------------- launch ----------------

extern "C" void kernel_launch(void* const* d_in, const int* in_sizes, int n_in,
                              void* d_out, int out_size, void* d_ws, size_t ws_size,
                              hipStream_t stream) {
    const float* x     = (const float*)d_in[0];
    const int*   ei    = (const int*)d_in[1];
    const int*   batch = (const int*)d_in[2];
    const float* bn0g = (const float*)d_in[3];
    const float* bn0b = (const float*)d_in[4];
    const float* bn1g = (const float*)d_in[5];
    const float* bn1b = (const float*)d_in[6];
    const float* bn2g = (const float*)d_in[7];
    const float* bn2b = (const float*)d_in[8];
    const float* W1  = (const float*)d_in[9];
    const float* b1  = (const float*)d_in[10];
    const float* W2  = (const float*)d_in[11];
    const float* b2  = (const float*)d_in[12];
    const float* W3  = (const float*)d_in[13];
    const float* b3  = (const float*)d_in[14];
    const float* Wl1 = (const float*)d_in[15];
    const float* bl1 = (const float*)d_in[16];
    const float* Wl2 = (const float*)d_in[17];
    const float* bl2 = (const float*)d_in[18];

    const int N = in_sizes[0] / 7;
    const int E = in_sizes[1] / 2;
    const int EN = E + N;
    const int G = out_size / 2;
    const int NB = (N + 255) / 256;
    const int NBK = (N + 255) / 256;        // buckets of 256 nodes
    const int NBIN = (EN + BIN_CH - 1) / BIN_CH;

    const int* src = ei;
    const int* dst = ei + E;

    char* w = (char*)d_ws;
    auto alloc = [&](size_t bytes) -> void* {
        void* p = (void*)w;
        w += ((bytes + 255) / 256) * 256;
        return p;
    };
    // Split H-tables:
    //   H1m [N,64]h | H1t [N,8]h | H2m [N,128]h | H2t [N,8]h
    size_t szH1m = (size_t)N * 64 * sizeof(__half);
    size_t szH1t = (size_t)N * 8 * sizeof(__half);
    size_t szH2m = (size_t)N * 128 * sizeof(__half);
    size_t szH2t = (size_t)N * 8 * sizeof(__half);
    char* regA = (char*)alloc(szH1m + szH1t + szH2m + szH2t);
    __half* H1m = (__half*)regA;
    __half* H1t = (__half*)(regA + szH1m);
    __half* H2m = (__half*)(regA + szH1m + szH1t);
    __half* H2t = (__half*)(regA + szH1m + szH1t + szH2m);

    __half* bufG = (__half*)alloc((size_t)N * 136 * sizeof(__half));  // gather outputs (max width)
    f16*    wp   = (f16*)  alloc((size_t)256 * 160 * sizeof(f16));
    float*  wrow = (float*)alloc(256 * sizeof(float));
    __half* xp   = (__half*)alloc((size_t)N * 8 * sizeof(__half));
    float* disq  = (float*)alloc((size_t)N * sizeof(float));
    float* rsum  = (float*)alloc((size_t)N * sizeof(float));
    int*   deg   = (int*)  alloc((size_t)N * sizeof(int));
    int*   rs    = (int*)  alloc((size_t)N * sizeof(int));
    int*   binned= (int*)  alloc((size_t)NBK * BCAP * sizeof(int));
    int*   csr_s = (int*)  alloc((size_t)NBK * BCAP * sizeof(int));
    float* csr_w = (float*)alloc((size_t)NBK * BCAP * sizeof(float));
    // contiguous zero-init region: 6 stat arrays (1KB each) + gcur (2KB) + pooled
    float* colsum0 = (float*)alloc(256 * sizeof(float));
    float* colsq0  = (float*)alloc(256 * sizeof(float));
    float* colsumA = (float*)alloc(256 * sizeof(float));
    float* colsqA  = (float*)alloc(256 * sizeof(float));
    float* colsumB = (float*)alloc(256 * sizeof(float));
    float* colsqB  = (float*)alloc(256 * sizeof(float));
    int*   gcur    = (int*)  alloc(512 * sizeof(int));
    float* pooled  = (float*)alloc((size_t)G * 199 * sizeof(float));
    int*   gstart  = (int*)  alloc((size_t)G * sizeof(int));
    int*   gend    = (int*)  alloc((size_t)G * sizeof(int));

    size_t zbytes = 6 * 1024 + 2048 + (((size_t)G * 199 * sizeof(float) + 255) / 256) * 256;
    hipMemsetAsync(colsum0, 0, zbytes, stream);   // stats + gcur + pooled, one node

    // ---- binned CSR build (single pass, fixed-capacity buckets) ----
    k_bin<<<NBIN, 256, 0, stream>>>(src, dst, E, EN, NBK, gcur, binned);
    k_bucket<<<NBK, 256, 0, stream>>>(binned, gcur, N, deg, rs, csr_s, disq);
    k_wfill<<<(N + 3) / 4, 256, 0, stream>>>(rs, deg, csr_s, disq, csr_w, N);

    const int GB = (N + 127) / 128;

    // ---- layer 1 ----
    k_padx_stats<<<NB, 256, 0, stream>>>(x, xp, N, colsum0, colsq0, batch, gstart, gend);
    k_prep<<<128, 256, 0, stream>>>(colsum0, colsq0, bn0g, bn0b, 1.f / (float)N,
                                    W1, 7, 71, 32, wp, wrow);
    k_gather8<<<(N + 255) / 256, 256, 0, stream>>>(xp, csr_s, csr_w, rs, deg, bufG, rsum, N);
    {
        dim3 grid(GB, 2);
        k_gemm_mfma<<<grid, 256, 0, stream>>>((const f16*)bufG, 8, wp, 32, rsum, wrow, b1,
                                              (f16*)H1m, 64, 64, (f16*)H1t, 72,
                                              colsumA, colsqA, 1, N, 71);
    }
    // ---- layer 2 ----
    k_prep<<<192, 256, 0, stream>>>(colsumA, colsqA, bn1g, bn1b, 1.f / (float)N,
                                    W2, 71, 135, 96, wp, wrow);
    k_gather_w<<<(N + 31) / 32, 256, 0, stream>>>(H1m, 64, 3,
                                                  rs, deg, csr_s, csr_w, bufG, 72, N);
    k_gather_tail<<<(N + 255) / 256, 256, 0, stream>>>(H1t, csr_s, csr_w, rs, deg,
                                                       bufG, 72, 64, N);
    {
        dim3 grid(GB, 3);
        k_gemm_mfma<<<grid, 256, 0, stream>>>((const f16*)bufG, 72, wp, 96, rsum, wrow, b2,
                                              (f16*)H2m, 128, 128, (f16*)H2t, 136,
                                              colsumB, colsqB, 1, N, 135);
    }
    // ---- layer 3 (GEMM fused with mean-pool; no H3) ----
    k_prep<<<256, 256, 0, stream>>>(colsumB, colsqB, bn2g, bn2b, 1.f / (float)N,
                                    W3, 135, 199, 160, wp, wrow);
    k_gather_w<<<(N + 15) / 16, 256, 0, stream>>>(H2m, 128, 4,
                                                  rs, deg, csr_s, csr_w, bufG, 136, N);
    k_gather_tail<<<(N + 255) / 256, 256, 0, stream>>>(H2t, csr_s, csr_w, rs, deg,
                                                       bufG, 136, 128, N);
    {
        dim3 grid(GB, 4);
        k_gemm_pool<<<grid, 256, 0, stream>>>((const f16*)bufG, 136, wp, 160, rsum, wrow, b3,
                                              batch, pooled, N, 199);
    }

    // ---- head ----
    k_mlp<<<G, 64, 0, stream>>>(pooled, gstart, gend, Wl1, bl1, Wl2, bl2, (float*)d_out, 199);
}

// Round 3
// 523.922 us; speedup vs baseline: 1.1460x; 1.1460x over previous
//
#include <hip/hip_runtime.h>
#include <hip/hip_fp16.h>

#define EPSV 1e-5f
#define BIN_CH 4096
#define BCAP 8192   // fixed bucket capacity (mean ~4348, sigma ~66 for uniform random)

typedef _Float16 f16;
typedef f16 half8 __attribute__((ext_vector_type(8)));
typedef float f32x4 __attribute__((ext_vector_type(4)));

// ---------------- binned CSR construction (single-pass, fixed-capacity buckets) ----

__global__ __launch_bounds__(256) void k_bin(const int* __restrict__ src,
                                             const int* __restrict__ dst, int E, int EN,
                                             int NBK, int* __restrict__ gcur,
                                             int* __restrict__ binned) {
    __shared__ int cnt[512];
    __shared__ int base[512];
    for (int b = threadIdx.x; b < 512; b += 256) cnt[b] = 0;
    __syncthreads();
    int i0 = blockIdx.x * BIN_CH;
    int i1 = i0 + BIN_CH; if (i1 > EN) i1 = EN;
    for (int i = i0 + threadIdx.x; i < i1; i += 256) {
        int d = (i < E) ? dst[i] : (i - E);
        atomicAdd(&cnt[d >> 8], 1);
    }
    __syncthreads();
    for (int b = threadIdx.x; b < NBK; b += 256)
        if (cnt[b]) base[b] = b * BCAP + atomicAdd(&gcur[b], cnt[b]);
    __syncthreads();
    for (int i = i0 + threadIdx.x; i < i1; i += 256) {
        int s, d;
        if (i < E) { s = src[i]; d = dst[i]; }
        else       { s = i - E; d = s; }
        int pos = atomicAdd(&base[d >> 8], 1);
        binned[pos] = s | ((d & 255) << 24);   // src < 2^24
    }
}

__global__ __launch_bounds__(256) void k_bucket(const int* __restrict__ binned,
                                                const int* __restrict__ gcur, int N,
                                                int* __restrict__ deg, int* __restrict__ rs,
                                                int* __restrict__ csr_s,
                                                float* __restrict__ disq) {
    __shared__ int deg_l[256];
    __shared__ int sc[256];
    __shared__ int cur_l[256];
    int b = blockIdx.x;
    int t = threadIdx.x;
    int start = b * BCAP, end = start + gcur[b];
    deg_l[t] = 0;
    __syncthreads();
    for (int i = start + t; i < end; i += 256)
        atomicAdd(&deg_l[((unsigned)binned[i]) >> 24], 1);
    __syncthreads();
    sc[t] = deg_l[t];
    __syncthreads();
    for (int off = 1; off < 256; off <<= 1) {
        int v = (t >= off) ? sc[t - off] : 0;
        __syncthreads();
        sc[t] += v;
        __syncthreads();
    }
    int rs_l = sc[t] - deg_l[t];
    int n = b * 256 + t;
    if (n < N) {
        deg[n] = deg_l[t];
        rs[n] = start + rs_l;
        disq[n] = rsqrtf((float)(deg_l[t] > 0 ? deg_l[t] : 1));
    }
    cur_l[t] = start + rs_l;
    __syncthreads();
    for (int i = start + t; i < end; i += 256) {
        int p = binned[i];
        int loc = ((unsigned)p) >> 24;
        int idx = atomicAdd(&cur_l[loc], 1);
        csr_s[idx] = p & 0xFFFFFF;
    }
}

__global__ __launch_bounds__(256) void k_wfill(const int* __restrict__ rs,
                                               const int* __restrict__ deg,
                                               const int* __restrict__ csr_s,
                                               const float* __restrict__ disq,
                                               float* __restrict__ csr_w, int N) {
    int wave = threadIdx.x >> 6, lane = threadIdx.x & 63;
    int n = blockIdx.x * 4 + wave;
    if (n >= N) return;
    int e0 = rs[n], dg = deg[n];
    float dn = disq[n];
    for (int j = lane; j < dg; j += 64) {
        int s = csr_s[e0 + j];
        csr_w[e0 + j] = disq[s] * dn;
    }
}

// ---- fused per-layer prep: scale/shift from raw sums + Wp_t + wrow ----

__global__ __launch_bounds__(256) void k_prep(
    const float* __restrict__ colsum, const float* __restrict__ colsq,
    const float* __restrict__ g, const float* __restrict__ b, float invN,
    const float* __restrict__ W, int Cin, int Cout, int KP,
    f16* __restrict__ Wp, float* __restrict__ wrow) {
    __shared__ float lsc[192];
    __shared__ float lsh[192];
    __shared__ float red[4];
    int t = threadIdx.x;
    int c = blockIdx.x;
    if (t < KP) {
        float scv = 0.f, shv = 0.f;
        if (t < Cin) {
            float m = colsum[t] * invN;
            float v = colsq[t] * invN - m * m;
            float rstd = rsqrtf(fmaxf(v, 0.f) + EPSV);
            scv = rstd * g[t];
            shv = b[t] - m * scv;
        }
        lsc[t] = scv; lsh[t] = shv;
    }
    __syncthreads();
    float part = 0.f;
    if (t < KP) {
        float wv = (t < Cin && c < Cout) ? W[(size_t)t * Cout + c] : 0.f;
        Wp[(size_t)c * KP + t] = (f16)(lsc[t] * wv);
        part = lsh[t] * wv;
    }
    for (int off = 32; off > 0; off >>= 1) part += __shfl_down(part, off);
    int lane = t & 63, wid = t >> 6;
    if (lane == 0) red[wid] = part;
    __syncthreads();
    if (t == 0) wrow[c] = red[0] + red[1] + red[2] + red[3];
}

// -- pad x [N,7] -> xp [N,8] fp16 + BN stats (direct atomics) + graph bounds --

__global__ __launch_bounds__(256) void k_padx_stats(const float* __restrict__ x,
                                                    __half* __restrict__ xp, int N,
                                                    float* __restrict__ colsum,
                                                    float* __restrict__ colsq,
                                                    const int* __restrict__ batch,
                                                    int* __restrict__ gstart,
                                                    int* __restrict__ gend) {
    __shared__ float ls[16];
    int t = threadIdx.x;
    int n = blockIdx.x * 256 + t;
    int lane = t & 63;
    if (t < 16) ls[t] = 0.f;
    __syncthreads();
    float v[7] = {0.f, 0.f, 0.f, 0.f, 0.f, 0.f, 0.f};
    if (n < N) {
#pragma unroll
        for (int j = 0; j < 7; ++j) v[j] = x[(size_t)n * 7 + j];
        __half h[8];
#pragma unroll
        for (int j = 0; j < 7; ++j) h[j] = __float2half(v[j]);
        h[7] = __float2half(0.f);
        *(float4*)(xp + (size_t)n * 8) = *(float4*)h;
        // graph segment bounds (batch sorted)
        int g = batch[n];
        int gp = (n == 0) ? -1 : batch[n - 1];
        if (gp != g) gstart[g] = n;
        int gn = (n == N - 1) ? -1 : batch[n + 1];
        if (gn != g) gend[g] = n + 1;
    }
#pragma unroll
    for (int j = 0; j < 7; ++j) {
        float s = v[j];
        float q = v[j] * v[j];
        for (int off = 32; off > 0; off >>= 1) {
            s += __shfl_down(s, off);
            q += __shfl_down(q, off);
        }
        if (lane == 0) {
            atomicAdd(&ls[j], s);
            atomicAdd(&ls[8 + j], q);
        }
    }
    __syncthreads();
    if (t < 8)               atomicAdd(&colsum[t], ls[t]);
    else if (t < 16)         atomicAdd(&colsq[t - 8], ls[t]);
}

// ---------------- gathers: G = S . X ----------------

// layer-1 gather: fp16 xp table (16B rows, 1.6MB -> L2-resident), also emits rsum
__global__ void k_gather8(const __half* __restrict__ xp, const int* __restrict__ csr_s,
                          const float* __restrict__ csr_w,
                          const int* __restrict__ rs, const int* __restrict__ deg,
                          __half* __restrict__ out, float* __restrict__ rsum, int N) {
    int n = blockIdx.x * blockDim.x + threadIdx.x;
    if (n >= N) return;
    int e0 = rs[n], eend = e0 + deg[n];
    float a0 = 0.f, a1 = 0.f, a2 = 0.f, a3 = 0.f, a4 = 0.f, a5 = 0.f, a6 = 0.f, a7 = 0.f;
    float ws = 0.f;
    for (int e = e0; e < eend; ++e) {
        int s = csr_s[e];
        float w = csr_w[e];
        ws += w;
        float4 r = *(const float4*)(xp + (size_t)s * 8);
        const __half2* hh = (const __half2*)&r;
        float2 q0 = __half22float2(hh[0]);
        float2 q1 = __half22float2(hh[1]);
        float2 q2 = __half22float2(hh[2]);
        float2 q3 = __half22float2(hh[3]);
        a0 = fmaf(w, q0.x, a0); a1 = fmaf(w, q0.y, a1);
        a2 = fmaf(w, q1.x, a2); a3 = fmaf(w, q1.y, a3);
        a4 = fmaf(w, q2.x, a4); a5 = fmaf(w, q2.y, a5);
        a6 = fmaf(w, q3.x, a6); a7 = fmaf(w, q3.y, a7);
    }
    rsum[n] = ws;
    __half h[8];
    h[0] = __float2half(a0); h[1] = __float2half(a1);
    h[2] = __float2half(a2); h[3] = __float2half(a3);
    h[4] = __float2half(a4); h[5] = __float2half(a5);
    h[6] = __float2half(a6); h[7] = __float2half(a7);
    *(float4*)(out + (size_t)n * 8) = *(float4*)h;
}

// tail gather: 8-half rows from small L2-resident table -> out cols [coff, coff+8)
__global__ __launch_bounds__(256) void k_gather_tail(
    const __half* __restrict__ At, const int* __restrict__ csr_s,
    const float* __restrict__ csr_w, const int* __restrict__ rs,
    const int* __restrict__ deg, __half* __restrict__ out, int SPo, int coff, int N) {
    int n = blockIdx.x * blockDim.x + threadIdx.x;
    if (n >= N) return;
    int e0 = rs[n], eend = e0 + deg[n];
    float a0 = 0.f, a1 = 0.f, a2 = 0.f, a3 = 0.f, a4 = 0.f, a5 = 0.f, a6 = 0.f, a7 = 0.f;
    for (int e = e0; e < eend; ++e) {
        int s = csr_s[e];
        float w = csr_w[e];
        float4 r = *(const float4*)(At + (size_t)s * 8);
        const __half2* hh = (const __half2*)&r;
        float2 q0 = __half22float2(hh[0]);
        float2 q1 = __half22float2(hh[1]);
        float2 q2 = __half22float2(hh[2]);
        float2 q3 = __half22float2(hh[3]);
        a0 = fmaf(w, q0.x, a0); a1 = fmaf(w, q0.y, a1);
        a2 = fmaf(w, q1.x, a2); a3 = fmaf(w, q1.y, a3);
        a4 = fmaf(w, q2.x, a4); a5 = fmaf(w, q2.y, a5);
        a6 = fmaf(w, q3.x, a6); a7 = fmaf(w, q3.y, a7);
    }
    __half2 h[4];
    h[0] = __floats2half2_rn(a0, a1);
    h[1] = __floats2half2_rn(a2, a3);
    h[2] = __floats2half2_rn(a4, a5);
    h[3] = __floats2half2_rn(a6, a7);
    *(float4*)(out + (size_t)n * SPo + coff) = *(float4*)h;
}

// multi-node-per-wave MAIN gather (power-of-2 chunks, all 64 lanes active):
//   Am rows of SPm halfs (128B-aligned); CH8 = SPm/8 chunks; SH = log2(CH8).
__global__ __launch_bounds__(256) void k_gather_w(
    const __half* __restrict__ Am, int SPm, int SH,
    const int* __restrict__ rs, const int* __restrict__ deg,
    const int* __restrict__ csr_s, const float* __restrict__ csr_w,
    __half* __restrict__ out, int SPo, int N) {
    int wave = threadIdx.x >> 6;
    int lane = threadIdx.x & 63;
    int sub = lane >> SH;
    int lsub = lane & ((1 << SH) - 1);
    int npw = 64 >> SH;
    int n = (blockIdx.x * 4 + wave) * npw + sub;
    bool active = (n < N);
    int e0 = 0, eend = 0;
    if (active) { e0 = rs[n]; eend = e0 + deg[n]; }
    const __half* base = Am + lsub * 8;
    float acc[8] = {};

    int e = e0;
    for (; e + 8 <= eend; e += 8) {
        int s[8]; float wv[8]; float4 r[8];
#pragma unroll
        for (int i = 0; i < 8; ++i) { s[i] = csr_s[e + i]; wv[i] = csr_w[e + i]; }
#pragma unroll
        for (int i = 0; i < 8; ++i) r[i] = *(const float4*)(base + (size_t)s[i] * SPm);
#pragma unroll
        for (int i = 0; i < 8; ++i) {
            float2 q0 = __half22float2(((const __half2*)&r[i])[0]);
            float2 q1 = __half22float2(((const __half2*)&r[i])[1]);
            float2 q2 = __half22float2(((const __half2*)&r[i])[2]);
            float2 q3 = __half22float2(((const __half2*)&r[i])[3]);
            acc[0] = fmaf(wv[i], q0.x, acc[0]); acc[1] = fmaf(wv[i], q0.y, acc[1]);
            acc[2] = fmaf(wv[i], q1.x, acc[2]); acc[3] = fmaf(wv[i], q1.y, acc[3]);
            acc[4] = fmaf(wv[i], q2.x, acc[4]); acc[5] = fmaf(wv[i], q2.y, acc[5]);
            acc[6] = fmaf(wv[i], q3.x, acc[6]); acc[7] = fmaf(wv[i], q3.y, acc[7]);
        }
    }
    for (; e + 4 <= eend; e += 4) {
        int s[4]; float wv[4]; float4 r[4];
#pragma unroll
        for (int i = 0; i < 4; ++i) { s[i] = csr_s[e + i]; wv[i] = csr_w[e + i]; }
#pragma unroll
        for (int i = 0; i < 4; ++i) r[i] = *(const float4*)(base + (size_t)s[i] * SPm);
#pragma unroll
        for (int i = 0; i < 4; ++i) {
            float2 q0 = __half22float2(((const __half2*)&r[i])[0]);
            float2 q1 = __half22float2(((const __half2*)&r[i])[1]);
            float2 q2 = __half22float2(((const __half2*)&r[i])[2]);
            float2 q3 = __half22float2(((const __half2*)&r[i])[3]);
            acc[0] = fmaf(wv[i], q0.x, acc[0]); acc[1] = fmaf(wv[i], q0.y, acc[1]);
            acc[2] = fmaf(wv[i], q1.x, acc[2]); acc[3] = fmaf(wv[i], q1.y, acc[3]);
            acc[4] = fmaf(wv[i], q2.x, acc[4]); acc[5] = fmaf(wv[i], q2.y, acc[5]);
            acc[6] = fmaf(wv[i], q3.x, acc[6]); acc[7] = fmaf(wv[i], q3.y, acc[7]);
        }
    }
    for (; e < eend; ++e) {
        int s = csr_s[e];
        float w = csr_w[e];
        float4 r = *(const float4*)(base + (size_t)s * SPm);
        float2 q0 = __half22float2(((const __half2*)&r)[0]);
        float2 q1 = __half22float2(((const __half2*)&r)[1]);
        float2 q2 = __half22float2(((const __half2*)&r)[2]);
        float2 q3 = __half22float2(((const __half2*)&r)[3]);
        acc[0] = fmaf(w, q0.x, acc[0]); acc[1] = fmaf(w, q0.y, acc[1]);
        acc[2] = fmaf(w, q1.x, acc[2]); acc[3] = fmaf(w, q1.y, acc[3]);
        acc[4] = fmaf(w, q2.x, acc[4]); acc[5] = fmaf(w, q2.y, acc[5]);
        acc[6] = fmaf(w, q3.x, acc[6]); acc[7] = fmaf(w, q3.y, acc[7]);
    }

    if (active) {
        __half2 h[4];
        h[0] = __floats2half2_rn(acc[0], acc[1]);
        h[1] = __floats2half2_rn(acc[2], acc[3]);
        h[2] = __floats2half2_rn(acc[4], acc[5]);
        h[3] = __floats2half2_rn(acc[6], acc[7]);
        *(float4*)(out + (size_t)n * SPo + lsub * 8) = *(float4*)h;
    }
}

// ------------- MFMA GEMM: H = relu(G @ Wp_t^T + rsum (x) wrow + bias) -------------
// Output routed to split tables: cols [0,MAIN) -> outM (stride SPm), [MAIN,TOTW) -> outT (stride 8).

__global__ __launch_bounds__(256) void k_gemm_mfma(
    const f16* __restrict__ A, int SPa,
    const f16* __restrict__ Bt, int KP,
    const float* __restrict__ rsum, const float* __restrict__ wrow,
    const float* __restrict__ bias,
    f16* __restrict__ outM, int SPm, int MAIN, f16* __restrict__ outT, int TOTW,
    float* __restrict__ colsum, float* __restrict__ colsq, int do_stats,
    int N, int Cout) {
    __shared__ f16 As[128][40];
    __shared__ float s_sum[64];
    __shared__ float s_sq[64];
    const int r0 = blockIdx.x * 128;
    const int c0 = blockIdx.y * 64;
    const int t = threadIdx.x;
    const int wave = t >> 6, lane = t & 63;
    const int l15 = lane & 15, quad = lane >> 4;

    if (t < 64) { s_sum[t] = 0.f; s_sq[t] = 0.f; }

    f32x4 zero4 = {0.f, 0.f, 0.f, 0.f};
    f32x4 acc[2][4];
#pragma unroll
    for (int mi = 0; mi < 2; ++mi)
#pragma unroll
        for (int ni = 0; ni < 4; ++ni) acc[mi][ni] = zero4;

    const int KT = KP >> 5;
    for (int kt = 0; kt < KT; ++kt) {
        int k0 = kt * 32;
        {
            int kcol = (t & 7) * 4;
            int rbase = t >> 3;
            int gk = k0 + kcol;
            bool kok = (gk + 4 <= SPa);
#pragma unroll
            for (int i = 0; i < 4; ++i) {
                int row = rbase + i * 32;
                int gr = r0 + row;
                ushort4 v = {0, 0, 0, 0};
                if (gr < N && kok)
                    v = *(const ushort4*)(A + (size_t)gr * SPa + gk);
                *(ushort4*)&As[row][kcol] = v;
            }
        }
        __syncthreads();
        half8 a0 = *(const half8*)&As[wave * 32 + l15][quad * 8];
        half8 a1 = *(const half8*)&As[wave * 32 + 16 + l15][quad * 8];
#pragma unroll
        for (int ni = 0; ni < 4; ++ni) {
            half8 b = *(const half8*)(Bt + (size_t)(c0 + ni * 16 + l15) * KP + k0 + quad * 8);
            acc[0][ni] = __builtin_amdgcn_mfma_f32_16x16x32_f16(a0, b, acc[0][ni], 0, 0, 0);
            acc[1][ni] = __builtin_amdgcn_mfma_f32_16x16x32_f16(a1, b, acc[1][ni], 0, 0, 0);
        }
        __syncthreads();
    }

    float wr[4], bi[4];
#pragma unroll
    for (int ni = 0; ni < 4; ++ni) {
        int gc = c0 + ni * 16 + l15;
        wr[ni] = wrow[gc];
        bi[ni] = (gc < Cout) ? bias[gc] : 0.f;
    }
    float ps[4] = {}, pq[4] = {};
#pragma unroll
    for (int mi = 0; mi < 2; ++mi) {
#pragma unroll
        for (int reg = 0; reg < 4; ++reg) {
            int gr = r0 + wave * 32 + mi * 16 + quad * 4 + reg;
            if (gr >= N) continue;
            float rsv = rsum[gr];
#pragma unroll
            for (int ni = 0; ni < 4; ++ni) {
                int gc = c0 + ni * 16 + l15;
                float o = acc[mi][ni][reg] + rsv * wr[ni] + bi[ni];
                o = fmaxf(o, 0.f);
                if (gc >= Cout) o = 0.f;
                ps[ni] += o; pq[ni] += o * o;
                if (gc < MAIN) {
                    if (gc < TOTW) outM[(size_t)gr * SPm + gc] = (f16)o;
                } else if (gc < TOTW) {
                    outT[(size_t)gr * 8 + (gc - MAIN)] = (f16)o;
                }
            }
        }
    }
    if (do_stats) {
#pragma unroll
        for (int ni = 0; ni < 4; ++ni) {
            int cl = ni * 16 + l15;
            atomicAdd(&s_sum[cl], ps[ni]);
            atomicAdd(&s_sq[cl], pq[ni]);
        }
        __syncthreads();
        if (t < 64 && c0 + t < Cout) {
            atomicAdd(&colsum[c0 + t], s_sum[t]);
            atomicAdd(&colsq[c0 + t], s_sq[t]);
        }
    }
}

// ---- layer-3 GEMM with fused mean-pool (fp32 staging tile, NO LDS atomics) ----

__global__ __launch_bounds__(256) void k_gemm_pool(
    const f16* __restrict__ A, int SPa,
    const f16* __restrict__ Bt, int KP,
    const float* __restrict__ rsum, const float* __restrict__ wrow,
    const float* __restrict__ bias, const int* __restrict__ batch,
    float* __restrict__ pooled, int N, int Cout) {
    __shared__ f16 As[128][40];
    __shared__ int sbat[128];
    __shared__ float s_tile[128][66];   // pad 66: store phase 2-way, read phase 2-way (free)
    const int r0 = blockIdx.x * 128;
    const int c0 = blockIdx.y * 64;
    const int t = threadIdx.x;
    const int wave = t >> 6, lane = t & 63;
    const int l15 = lane & 15, quad = lane >> 4;

    if (t < 128) {
        int gr = r0 + t;
        sbat[t] = batch[(gr < N) ? gr : (N - 1)];
    }

    f32x4 zero4 = {0.f, 0.f, 0.f, 0.f};
    f32x4 acc[2][4];
#pragma unroll
    for (int mi = 0; mi < 2; ++mi)
#pragma unroll
        for (int ni = 0; ni < 4; ++ni) acc[mi][ni] = zero4;

    const int KT = KP >> 5;
    for (int kt = 0; kt < KT; ++kt) {
        int k0 = kt * 32;
        {
            int kcol = (t & 7) * 4;
            int rbase = t >> 3;
            int gk = k0 + kcol;
            bool kok = (gk + 4 <= SPa);
#pragma unroll
            for (int i = 0; i < 4; ++i) {
                int row = rbase + i * 32;
                int gr = r0 + row;
                ushort4 v = {0, 0, 0, 0};
                if (gr < N && kok)
                    v = *(const ushort4*)(A + (size_t)gr * SPa + gk);
                *(ushort4*)&As[row][kcol] = v;
            }
        }
        __syncthreads();
        half8 a0 = *(const half8*)&As[wave * 32 + l15][quad * 8];
        half8 a1 = *(const half8*)&As[wave * 32 + 16 + l15][quad * 8];
#pragma unroll
        for (int ni = 0; ni < 4; ++ni) {
            half8 b = *(const half8*)(Bt + (size_t)(c0 + ni * 16 + l15) * KP + k0 + quad * 8);
            acc[0][ni] = __builtin_amdgcn_mfma_f32_16x16x32_f16(a0, b, acc[0][ni], 0, 0, 0);
            acc[1][ni] = __builtin_amdgcn_mfma_f32_16x16x32_f16(a1, b, acc[1][ni], 0, 0, 0);
        }
        __syncthreads();
    }

    // zero-init tile only when this block has rows >= N (block-uniform condition)
    if (r0 + 128 > N) {
        for (int i = t; i < 128 * 66; i += 256) ((float*)s_tile)[i] = 0.f;
        __syncthreads();
    }

    float wr[4], bi[4];
#pragma unroll
    for (int ni = 0; ni < 4; ++ni) {
        int gc = c0 + ni * 16 + l15;
        wr[ni] = wrow[gc];
        bi[ni] = (gc < Cout) ? bias[gc] : 0.f;
    }
    // store phase: each (row,col) has exactly one owner -> plain stores
#pragma unroll
    for (int mi = 0; mi < 2; ++mi) {
#pragma unroll
        for (int reg = 0; reg < 4; ++reg) {
            int lrow = wave * 32 + mi * 16 + quad * 4 + reg;
            int gr = r0 + lrow;
            if (gr >= N) continue;
            float rsv = rsum[gr];
#pragma unroll
            for (int ni = 0; ni < 4; ++ni) {
                float o = acc[mi][ni][reg] + rsv * wr[ni] + bi[ni];
                o = fmaxf(o, 0.f);
                s_tile[lrow][ni * 16 + l15] = o;
            }
        }
    }
    __syncthreads();
    // segmented column reduce: 4 threads/col, 32 rows each; batch sorted
    {
        int c = t & 63, ch = t >> 6;
        int gc = c0 + c;
        if (gc < Cout) {
            int rbeg = ch * 32;
            int cg = sbat[rbeg];
            float acc2 = 0.f;
            for (int r = rbeg; r < rbeg + 32; ++r) {
                int g = sbat[r];
                if (g != cg) {
                    if (acc2 != 0.f) atomicAdd(&pooled[(size_t)cg * Cout + gc], acc2);
                    acc2 = 0.f; cg = g;
                }
                acc2 += s_tile[r][c];
            }
            if (acc2 != 0.f) atomicAdd(&pooled[(size_t)cg * Cout + gc], acc2);
        }
    }
}

// ---------------- head MLP ----------------

__global__ void k_mlp(const float* __restrict__ pooled, const int* __restrict__ gstart,
                      const int* __restrict__ gend,
                      const float* __restrict__ Wl1, const float* __restrict__ bl1,
                      const float* __restrict__ Wl2, const float* __restrict__ bl2,
                      float* __restrict__ out, int C) {
    __shared__ float p[199];
    __shared__ float t1[49];
    int g = blockIdx.x;
    int cnt = gend[g] - gstart[g];
    float inv = 1.f / (float)(cnt > 1 ? cnt : 1);
    for (int k = threadIdx.x; k < C; k += blockDim.x) p[k] = pooled[g * C + k] * inv;
    __syncthreads();
    if (threadIdx.x < 49) {
        float acc = bl1[threadIdx.x];
        for (int k = 0; k < C; ++k) acc += p[k] * Wl1[k * 49 + threadIdx.x];
        t1[threadIdx.x] = acc;
    }
    __syncthreads();
    if (threadIdx.x < 2) {
        float acc = bl2[threadIdx.x];
        for (int k = 0; k < 49; ++k) acc += t1[k] * Wl2[k * 2 + threadIdx.x];
        out[g * 2 + threadIdx.x] = acc;
    }
}

// ---------------- launch ----------------

extern "C" void kernel_launch(void* const* d_in, const int* in_sizes, int n_in,
                              void* d_out, int out_size, void* d_ws, size_t ws_size,
                              hipStream_t stream) {
    const float* x     = (const float*)d_in[0];
    const int*   ei    = (const int*)d_in[1];
    const int*   batch = (const int*)d_in[2];
    const float* bn0g = (const float*)d_in[3];
    const float* bn0b = (const float*)d_in[4];
    const float* bn1g = (const float*)d_in[5];
    const float* bn1b = (const float*)d_in[6];
    const float* bn2g = (const float*)d_in[7];
    const float* bn2b = (const float*)d_in[8];
    const float* W1  = (const float*)d_in[9];
    const float* b1  = (const float*)d_in[10];
    const float* W2  = (const float*)d_in[11];
    const float* b2  = (const float*)d_in[12];
    const float* W3  = (const float*)d_in[13];
    const float* b3  = (const float*)d_in[14];
    const float* Wl1 = (const float*)d_in[15];
    const float* bl1 = (const float*)d_in[16];
    const float* Wl2 = (const float*)d_in[17];
    const float* bl2 = (const float*)d_in[18];

    const int N = in_sizes[0] / 7;
    const int E = in_sizes[1] / 2;
    const int EN = E + N;
    const int G = out_size / 2;
    const int NB = (N + 255) / 256;
    const int NBK = (N + 255) / 256;        // buckets of 256 nodes
    const int NBIN = (EN + BIN_CH - 1) / BIN_CH;

    const int* src = ei;
    const int* dst = ei + E;

    char* w = (char*)d_ws;
    auto alloc = [&](size_t bytes) -> void* {
        void* p = (void*)w;
        w += ((bytes + 255) / 256) * 256;
        return p;
    };
    // Split H-tables:
    //   H1m [N,64]h | H1t [N,8]h | H2m [N,128]h | H2t [N,8]h
    size_t szH1m = (size_t)N * 64 * sizeof(__half);
    size_t szH1t = (size_t)N * 8 * sizeof(__half);
    size_t szH2m = (size_t)N * 128 * sizeof(__half);
    size_t szH2t = (size_t)N * 8 * sizeof(__half);
    char* regA = (char*)alloc(szH1m + szH1t + szH2m + szH2t);
    __half* H1m = (__half*)regA;
    __half* H1t = (__half*)(regA + szH1m);
    __half* H2m = (__half*)(regA + szH1m + szH1t);
    __half* H2t = (__half*)(regA + szH1m + szH1t + szH2m);

    __half* bufG = (__half*)alloc((size_t)N * 136 * sizeof(__half));  // gather outputs (max width)
    f16*    wp   = (f16*)  alloc((size_t)256 * 160 * sizeof(f16));
    float*  wrow = (float*)alloc(256 * sizeof(float));
    __half* xp   = (__half*)alloc((size_t)N * 8 * sizeof(__half));
    float* disq  = (float*)alloc((size_t)N * sizeof(float));
    float* rsum  = (float*)alloc((size_t)N * sizeof(float));
    int*   deg   = (int*)  alloc((size_t)N * sizeof(int));
    int*   rs    = (int*)  alloc((size_t)N * sizeof(int));
    int*   binned= (int*)  alloc((size_t)NBK * BCAP * sizeof(int));
    int*   csr_s = (int*)  alloc((size_t)NBK * BCAP * sizeof(int));
    float* csr_w = (float*)alloc((size_t)NBK * BCAP * sizeof(float));
    // contiguous zero-init region: 6 stat arrays (1KB each) + gcur (2KB) + pooled
    float* colsum0 = (float*)alloc(256 * sizeof(float));
    float* colsq0  = (float*)alloc(256 * sizeof(float));
    float* colsumA = (float*)alloc(256 * sizeof(float));
    float* colsqA  = (float*)alloc(256 * sizeof(float));
    float* colsumB = (float*)alloc(256 * sizeof(float));
    float* colsqB  = (float*)alloc(256 * sizeof(float));
    int*   gcur    = (int*)  alloc(512 * sizeof(int));
    float* pooled  = (float*)alloc((size_t)G * 199 * sizeof(float));
    int*   gstart  = (int*)  alloc((size_t)G * sizeof(int));
    int*   gend    = (int*)  alloc((size_t)G * sizeof(int));

    size_t zbytes = 6 * 1024 + 2048 + (((size_t)G * 199 * sizeof(float) + 255) / 256) * 256;
    hipMemsetAsync(colsum0, 0, zbytes, stream);   // stats + gcur + pooled, one node

    // ---- binned CSR build (single pass, fixed-capacity buckets) ----
    k_bin<<<NBIN, 256, 0, stream>>>(src, dst, E, EN, NBK, gcur, binned);
    k_bucket<<<NBK, 256, 0, stream>>>(binned, gcur, N, deg, rs, csr_s, disq);
    k_wfill<<<(N + 3) / 4, 256, 0, stream>>>(rs, deg, csr_s, disq, csr_w, N);

    const int GB = (N + 127) / 128;

    // ---- layer 1 ----
    k_padx_stats<<<NB, 256, 0, stream>>>(x, xp, N, colsum0, colsq0, batch, gstart, gend);
    k_prep<<<128, 256, 0, stream>>>(colsum0, colsq0, bn0g, bn0b, 1.f / (float)N,
                                    W1, 7, 71, 32, wp, wrow);
    k_gather8<<<(N + 255) / 256, 256, 0, stream>>>(xp, csr_s, csr_w, rs, deg, bufG, rsum, N);
    {
        dim3 grid(GB, 2);
        k_gemm_mfma<<<grid, 256, 0, stream>>>((const f16*)bufG, 8, wp, 32, rsum, wrow, b1,
                                              (f16*)H1m, 64, 64, (f16*)H1t, 72,
                                              colsumA, colsqA, 1, N, 71);
    }
    // ---- layer 2 ----
    k_prep<<<192, 256, 0, stream>>>(colsumA, colsqA, bn1g, bn1b, 1.f / (float)N,
                                    W2, 71, 135, 96, wp, wrow);
    k_gather_w<<<(N + 31) / 32, 256, 0, stream>>>(H1m, 64, 3,
                                                  rs, deg, csr_s, csr_w, bufG, 72, N);
    k_gather_tail<<<(N + 255) / 256, 256, 0, stream>>>(H1t, csr_s, csr_w, rs, deg,
                                                       bufG, 72, 64, N);
    {
        dim3 grid(GB, 3);
        k_gemm_mfma<<<grid, 256, 0, stream>>>((const f16*)bufG, 72, wp, 96, rsum, wrow, b2,
                                              (f16*)H2m, 128, 128, (f16*)H2t, 136,
                                              colsumB, colsqB, 1, N, 135);
    }
    // ---- layer 3 (GEMM fused with mean-pool; no H3) ----
    k_prep<<<256, 256, 0, stream>>>(colsumB, colsqB, bn2g, bn2b, 1.f / (float)N,
                                    W3, 135, 199, 160, wp, wrow);
    k_gather_w<<<(N + 15) / 16, 256, 0, stream>>>(H2m, 128, 4,
                                                  rs, deg, csr_s, csr_w, bufG, 136, N);
    k_gather_tail<<<(N + 255) / 256, 256, 0, stream>>>(H2t, csr_s, csr_w, rs, deg,
                                                       bufG, 136, 128, N);
    {
        dim3 grid(GB, 4);
        k_gemm_pool<<<grid, 256, 0, stream>>>((const f16*)bufG, 136, wp, 160, rsum, wrow, b3,
                                              batch, pooled, N, 199);
    }

    // ---- head ----
    k_mlp<<<G, 64, 0, stream>>>(pooled, gstart, gend, Wl1, bl1, Wl2, bl2, (float*)d_out, 199);
}

// Round 4
// 504.547 us; speedup vs baseline: 1.1900x; 1.0384x over previous
//
#include <hip/hip_runtime.h>
#include <hip/hip_fp16.h>

#define EPSV 1e-5f
#define BIN_CH 4096
#define BCAP 8192   // fixed bucket capacity (mean ~4348, sigma ~66 for uniform random)

typedef _Float16 f16;
typedef f16 half8 __attribute__((ext_vector_type(8)));
typedef float f32x4 __attribute__((ext_vector_type(4)));

// ---------------- binned CSR construction (single-pass, fixed-capacity buckets) ----

__global__ __launch_bounds__(256) void k_bin(const int* __restrict__ src,
                                             const int* __restrict__ dst, int E, int EN,
                                             int NBK, int* __restrict__ gcur,
                                             int* __restrict__ binned) {
    __shared__ int cnt[512];
    __shared__ int base[512];
    for (int b = threadIdx.x; b < 512; b += 256) cnt[b] = 0;
    __syncthreads();
    int i0 = blockIdx.x * BIN_CH;
    int i1 = i0 + BIN_CH; if (i1 > EN) i1 = EN;
    for (int i = i0 + threadIdx.x; i < i1; i += 256) {
        int d = (i < E) ? dst[i] : (i - E);
        atomicAdd(&cnt[d >> 8], 1);
    }
    __syncthreads();
    for (int b = threadIdx.x; b < NBK; b += 256)
        if (cnt[b]) base[b] = b * BCAP + atomicAdd(&gcur[b], cnt[b]);
    __syncthreads();
    for (int i = i0 + threadIdx.x; i < i1; i += 256) {
        int s, d;
        if (i < E) { s = src[i]; d = dst[i]; }
        else       { s = i - E; d = s; }
        int pos = atomicAdd(&base[d >> 8], 1);
        binned[pos] = s | ((d & 255) << 24);   // src < 2^24
    }
}

__global__ __launch_bounds__(256) void k_bucket(const int* __restrict__ binned,
                                                const int* __restrict__ gcur, int N,
                                                int* __restrict__ deg, int* __restrict__ rs,
                                                int* __restrict__ csr_s,
                                                float* __restrict__ disq) {
    __shared__ int deg_l[256];
    __shared__ int sc[256];
    __shared__ int cur_l[256];
    int b = blockIdx.x;
    int t = threadIdx.x;
    int start = b * BCAP, end = start + gcur[b];
    deg_l[t] = 0;
    __syncthreads();
    for (int i = start + t; i < end; i += 256)
        atomicAdd(&deg_l[((unsigned)binned[i]) >> 24], 1);
    __syncthreads();
    sc[t] = deg_l[t];
    __syncthreads();
    for (int off = 1; off < 256; off <<= 1) {
        int v = (t >= off) ? sc[t - off] : 0;
        __syncthreads();
        sc[t] += v;
        __syncthreads();
    }
    int rs_l = sc[t] - deg_l[t];
    int n = b * 256 + t;
    if (n < N) {
        deg[n] = deg_l[t];
        rs[n] = start + rs_l;
        disq[n] = rsqrtf((float)(deg_l[t] > 0 ? deg_l[t] : 1));
    }
    cur_l[t] = start + rs_l;
    __syncthreads();
    for (int i = start + t; i < end; i += 256) {
        int p = binned[i];
        int loc = ((unsigned)p) >> 24;
        int idx = atomicAdd(&cur_l[loc], 1);
        csr_s[idx] = p & 0xFFFFFF;
    }
}

__global__ __launch_bounds__(256) void k_wfill(const int* __restrict__ rs,
                                               const int* __restrict__ deg,
                                               const int* __restrict__ csr_s,
                                               const float* __restrict__ disq,
                                               float* __restrict__ csr_w, int N) {
    int wave = threadIdx.x >> 6, lane = threadIdx.x & 63;
    int n = blockIdx.x * 4 + wave;
    if (n >= N) return;
    int e0 = rs[n], dg = deg[n];
    float dn = disq[n];
    for (int j = lane; j < dg; j += 64) {
        int s = csr_s[e0 + j];
        csr_w[e0 + j] = disq[s] * dn;
    }
}

// ---- fused per-layer prep: scale/shift from raw sums + Wp_t + wrow ----

__global__ __launch_bounds__(256) void k_prep(
    const float* __restrict__ colsum, const float* __restrict__ colsq,
    const float* __restrict__ g, const float* __restrict__ b, float invN,
    const float* __restrict__ W, int Cin, int Cout, int KP,
    f16* __restrict__ Wp, float* __restrict__ wrow) {
    __shared__ float lsc[192];
    __shared__ float lsh[192];
    __shared__ float red[4];
    int t = threadIdx.x;
    int c = blockIdx.x;
    if (t < KP) {
        float scv = 0.f, shv = 0.f;
        if (t < Cin) {
            float m = colsum[t] * invN;
            float v = colsq[t] * invN - m * m;
            float rstd = rsqrtf(fmaxf(v, 0.f) + EPSV);
            scv = rstd * g[t];
            shv = b[t] - m * scv;
        }
        lsc[t] = scv; lsh[t] = shv;
    }
    __syncthreads();
    float part = 0.f;
    if (t < KP) {
        float wv = (t < Cin && c < Cout) ? W[(size_t)t * Cout + c] : 0.f;
        Wp[(size_t)c * KP + t] = (f16)(lsc[t] * wv);
        part = lsh[t] * wv;
    }
    for (int off = 32; off > 0; off >>= 1) part += __shfl_down(part, off);
    int lane = t & 63, wid = t >> 6;
    if (lane == 0) red[wid] = part;
    __syncthreads();
    if (t == 0) wrow[c] = red[0] + red[1] + red[2] + red[3];
}

// -- pad x [N,7] -> xp [N,8] fp16 + BN stats (direct atomics) + graph bounds --

__global__ __launch_bounds__(256) void k_padx_stats(const float* __restrict__ x,
                                                    __half* __restrict__ xp, int N,
                                                    float* __restrict__ colsum,
                                                    float* __restrict__ colsq,
                                                    const int* __restrict__ batch,
                                                    int* __restrict__ gstart,
                                                    int* __restrict__ gend) {
    __shared__ float ls[16];
    int t = threadIdx.x;
    int n = blockIdx.x * 256 + t;
    int lane = t & 63;
    if (t < 16) ls[t] = 0.f;
    __syncthreads();
    float v[7] = {0.f, 0.f, 0.f, 0.f, 0.f, 0.f, 0.f};
    if (n < N) {
#pragma unroll
        for (int j = 0; j < 7; ++j) v[j] = x[(size_t)n * 7 + j];
        __half h[8];
#pragma unroll
        for (int j = 0; j < 7; ++j) h[j] = __float2half(v[j]);
        h[7] = __float2half(0.f);
        *(float4*)(xp + (size_t)n * 8) = *(float4*)h;
        // graph segment bounds (batch sorted)
        int g = batch[n];
        int gp = (n == 0) ? -1 : batch[n - 1];
        if (gp != g) gstart[g] = n;
        int gn = (n == N - 1) ? -1 : batch[n + 1];
        if (gn != g) gend[g] = n + 1;
    }
#pragma unroll
    for (int j = 0; j < 7; ++j) {
        float s = v[j];
        float q = v[j] * v[j];
        for (int off = 32; off > 0; off >>= 1) {
            s += __shfl_down(s, off);
            q += __shfl_down(q, off);
        }
        if (lane == 0) {
            atomicAdd(&ls[j], s);
            atomicAdd(&ls[8 + j], q);
        }
    }
    __syncthreads();
    if (t < 8)               atomicAdd(&colsum[t], ls[t]);
    else if (t < 16)         atomicAdd(&colsq[t - 8], ls[t]);
}

// ---------------- gathers: G = S . X ----------------

// layer-1 gather: fp16 xp table (16B rows, 1.6MB -> L2-resident), also emits rsum
__global__ void k_gather8(const __half* __restrict__ xp, const int* __restrict__ csr_s,
                          const float* __restrict__ csr_w,
                          const int* __restrict__ rs, const int* __restrict__ deg,
                          __half* __restrict__ out, float* __restrict__ rsum, int N) {
    int n = blockIdx.x * blockDim.x + threadIdx.x;
    if (n >= N) return;
    int e0 = rs[n], eend = e0 + deg[n];
    float a0 = 0.f, a1 = 0.f, a2 = 0.f, a3 = 0.f, a4 = 0.f, a5 = 0.f, a6 = 0.f, a7 = 0.f;
    float ws = 0.f;
    for (int e = e0; e < eend; ++e) {
        int s = csr_s[e];
        float w = csr_w[e];
        ws += w;
        float4 r = *(const float4*)(xp + (size_t)s * 8);
        const __half2* hh = (const __half2*)&r;
        float2 q0 = __half22float2(hh[0]);
        float2 q1 = __half22float2(hh[1]);
        float2 q2 = __half22float2(hh[2]);
        float2 q3 = __half22float2(hh[3]);
        a0 = fmaf(w, q0.x, a0); a1 = fmaf(w, q0.y, a1);
        a2 = fmaf(w, q1.x, a2); a3 = fmaf(w, q1.y, a3);
        a4 = fmaf(w, q2.x, a4); a5 = fmaf(w, q2.y, a5);
        a6 = fmaf(w, q3.x, a6); a7 = fmaf(w, q3.y, a7);
    }
    rsum[n] = ws;
    __half h[8];
    h[0] = __float2half(a0); h[1] = __float2half(a1);
    h[2] = __float2half(a2); h[3] = __float2half(a3);
    h[4] = __float2half(a4); h[5] = __float2half(a5);
    h[6] = __float2half(a6); h[7] = __float2half(a7);
    *(float4*)(out + (size_t)n * 8) = *(float4*)h;
}

// tail gather: 8-half rows from small L2-resident table -> out cols [coff, coff+8)
__global__ __launch_bounds__(256) void k_gather_tail(
    const __half* __restrict__ At, const int* __restrict__ csr_s,
    const float* __restrict__ csr_w, const int* __restrict__ rs,
    const int* __restrict__ deg, __half* __restrict__ out, int SPo, int coff, int N) {
    int n = blockIdx.x * blockDim.x + threadIdx.x;
    if (n >= N) return;
    int e0 = rs[n], eend = e0 + deg[n];
    float a0 = 0.f, a1 = 0.f, a2 = 0.f, a3 = 0.f, a4 = 0.f, a5 = 0.f, a6 = 0.f, a7 = 0.f;
    for (int e = e0; e < eend; ++e) {
        int s = csr_s[e];
        float w = csr_w[e];
        float4 r = *(const float4*)(At + (size_t)s * 8);
        const __half2* hh = (const __half2*)&r;
        float2 q0 = __half22float2(hh[0]);
        float2 q1 = __half22float2(hh[1]);
        float2 q2 = __half22float2(hh[2]);
        float2 q3 = __half22float2(hh[3]);
        a0 = fmaf(w, q0.x, a0); a1 = fmaf(w, q0.y, a1);
        a2 = fmaf(w, q1.x, a2); a3 = fmaf(w, q1.y, a3);
        a4 = fmaf(w, q2.x, a4); a5 = fmaf(w, q2.y, a5);
        a6 = fmaf(w, q3.x, a6); a7 = fmaf(w, q3.y, a7);
    }
    __half2 h[4];
    h[0] = __floats2half2_rn(a0, a1);
    h[1] = __floats2half2_rn(a2, a3);
    h[2] = __floats2half2_rn(a4, a5);
    h[3] = __floats2half2_rn(a6, a7);
    *(float4*)(out + (size_t)n * SPo + coff) = *(float4*)h;
}

// multi-node-per-wave MAIN gather (power-of-2 chunks, all 64 lanes active):
//   Am rows of SPm halfs (128B-aligned); CH8 = SPm/8 chunks; SH = log2(CH8).
__global__ __launch_bounds__(256) void k_gather_w(
    const __half* __restrict__ Am, int SPm, int SH,
    const int* __restrict__ rs, const int* __restrict__ deg,
    const int* __restrict__ csr_s, const float* __restrict__ csr_w,
    __half* __restrict__ out, int SPo, int N) {
    int wave = threadIdx.x >> 6;
    int lane = threadIdx.x & 63;
    int sub = lane >> SH;
    int lsub = lane & ((1 << SH) - 1);
    int npw = 64 >> SH;
    int n = (blockIdx.x * 4 + wave) * npw + sub;
    bool active = (n < N);
    int e0 = 0, eend = 0;
    if (active) { e0 = rs[n]; eend = e0 + deg[n]; }
    const __half* base = Am + lsub * 8;
    float acc[8] = {};

    int e = e0;
    for (; e + 8 <= eend; e += 8) {
        int s[8]; float wv[8]; float4 r[8];
#pragma unroll
        for (int i = 0; i < 8; ++i) { s[i] = csr_s[e + i]; wv[i] = csr_w[e + i]; }
#pragma unroll
        for (int i = 0; i < 8; ++i) r[i] = *(const float4*)(base + (size_t)s[i] * SPm);
#pragma unroll
        for (int i = 0; i < 8; ++i) {
            float2 q0 = __half22float2(((const __half2*)&r[i])[0]);
            float2 q1 = __half22float2(((const __half2*)&r[i])[1]);
            float2 q2 = __half22float2(((const __half2*)&r[i])[2]);
            float2 q3 = __half22float2(((const __half2*)&r[i])[3]);
            acc[0] = fmaf(wv[i], q0.x, acc[0]); acc[1] = fmaf(wv[i], q0.y, acc[1]);
            acc[2] = fmaf(wv[i], q1.x, acc[2]); acc[3] = fmaf(wv[i], q1.y, acc[3]);
            acc[4] = fmaf(wv[i], q2.x, acc[4]); acc[5] = fmaf(wv[i], q2.y, acc[5]);
            acc[6] = fmaf(wv[i], q3.x, acc[6]); acc[7] = fmaf(wv[i], q3.y, acc[7]);
        }
    }
    for (; e + 4 <= eend; e += 4) {
        int s[4]; float wv[4]; float4 r[4];
#pragma unroll
        for (int i = 0; i < 4; ++i) { s[i] = csr_s[e + i]; wv[i] = csr_w[e + i]; }
#pragma unroll
        for (int i = 0; i < 4; ++i) r[i] = *(const float4*)(base + (size_t)s[i] * SPm);
#pragma unroll
        for (int i = 0; i < 4; ++i) {
            float2 q0 = __half22float2(((const __half2*)&r[i])[0]);
            float2 q1 = __half22float2(((const __half2*)&r[i])[1]);
            float2 q2 = __half22float2(((const __half2*)&r[i])[2]);
            float2 q3 = __half22float2(((const __half2*)&r[i])[3]);
            acc[0] = fmaf(wv[i], q0.x, acc[0]); acc[1] = fmaf(wv[i], q0.y, acc[1]);
            acc[2] = fmaf(wv[i], q1.x, acc[2]); acc[3] = fmaf(wv[i], q1.y, acc[3]);
            acc[4] = fmaf(wv[i], q2.x, acc[4]); acc[5] = fmaf(wv[i], q2.y, acc[5]);
            acc[6] = fmaf(wv[i], q3.x, acc[6]); acc[7] = fmaf(wv[i], q3.y, acc[7]);
        }
    }
    for (; e < eend; ++e) {
        int s = csr_s[e];
        float w = csr_w[e];
        float4 r = *(const float4*)(base + (size_t)s * SPm);
        float2 q0 = __half22float2(((const __half2*)&r)[0]);
        float2 q1 = __half22float2(((const __half2*)&r)[1]);
        float2 q2 = __half22float2(((const __half2*)&r)[2]);
        float2 q3 = __half22float2(((const __half2*)&r)[3]);
        acc[0] = fmaf(w, q0.x, acc[0]); acc[1] = fmaf(w, q0.y, acc[1]);
        acc[2] = fmaf(w, q1.x, acc[2]); acc[3] = fmaf(w, q1.y, acc[3]);
        acc[4] = fmaf(w, q2.x, acc[4]); acc[5] = fmaf(w, q2.y, acc[5]);
        acc[6] = fmaf(w, q3.x, acc[6]); acc[7] = fmaf(w, q3.y, acc[7]);
    }

    if (active) {
        __half2 h[4];
        h[0] = __floats2half2_rn(acc[0], acc[1]);
        h[1] = __floats2half2_rn(acc[2], acc[3]);
        h[2] = __floats2half2_rn(acc[4], acc[5]);
        h[3] = __floats2half2_rn(acc[6], acc[7]);
        *(float4*)(out + (size_t)n * SPo + lsub * 8) = *(float4*)h;
    }
}

// ------------- MFMA GEMM: H = relu(G @ Wp_t^T + rsum (x) wrow + bias) -------------
// Output routed to split tables: cols [0,MAIN) -> outM (stride SPm), [MAIN,TOTW) -> outT (stride 8).

__global__ __launch_bounds__(256) void k_gemm_mfma(
    const f16* __restrict__ A, int SPa,
    const f16* __restrict__ Bt, int KP,
    const float* __restrict__ rsum, const float* __restrict__ wrow,
    const float* __restrict__ bias,
    f16* __restrict__ outM, int SPm, int MAIN, f16* __restrict__ outT, int TOTW,
    float* __restrict__ colsum, float* __restrict__ colsq, int do_stats,
    int N, int Cout) {
    __shared__ f16 As[128][40];
    __shared__ float s_sum[64];
    __shared__ float s_sq[64];
    const int r0 = blockIdx.x * 128;
    const int c0 = blockIdx.y * 64;
    const int t = threadIdx.x;
    const int wave = t >> 6, lane = t & 63;
    const int l15 = lane & 15, quad = lane >> 4;

    if (t < 64) { s_sum[t] = 0.f; s_sq[t] = 0.f; }

    f32x4 zero4 = {0.f, 0.f, 0.f, 0.f};
    f32x4 acc[2][4];
#pragma unroll
    for (int mi = 0; mi < 2; ++mi)
#pragma unroll
        for (int ni = 0; ni < 4; ++ni) acc[mi][ni] = zero4;

    const int KT = KP >> 5;
    for (int kt = 0; kt < KT; ++kt) {
        int k0 = kt * 32;
        {
            int kcol = (t & 7) * 4;
            int rbase = t >> 3;
            int gk = k0 + kcol;
            bool kok = (gk + 4 <= SPa);
#pragma unroll
            for (int i = 0; i < 4; ++i) {
                int row = rbase + i * 32;
                int gr = r0 + row;
                ushort4 v = {0, 0, 0, 0};
                if (gr < N && kok)
                    v = *(const ushort4*)(A + (size_t)gr * SPa + gk);
                *(ushort4*)&As[row][kcol] = v;
            }
        }
        __syncthreads();
        half8 a0 = *(const half8*)&As[wave * 32 + l15][quad * 8];
        half8 a1 = *(const half8*)&As[wave * 32 + 16 + l15][quad * 8];
#pragma unroll
        for (int ni = 0; ni < 4; ++ni) {
            half8 b = *(const half8*)(Bt + (size_t)(c0 + ni * 16 + l15) * KP + k0 + quad * 8);
            acc[0][ni] = __builtin_amdgcn_mfma_f32_16x16x32_f16(a0, b, acc[0][ni], 0, 0, 0);
            acc[1][ni] = __builtin_amdgcn_mfma_f32_16x16x32_f16(a1, b, acc[1][ni], 0, 0, 0);
        }
        __syncthreads();
    }

    float wr[4], bi[4];
#pragma unroll
    for (int ni = 0; ni < 4; ++ni) {
        int gc = c0 + ni * 16 + l15;
        wr[ni] = wrow[gc];
        bi[ni] = (gc < Cout) ? bias[gc] : 0.f;
    }
    float ps[4] = {}, pq[4] = {};
#pragma unroll
    for (int mi = 0; mi < 2; ++mi) {
#pragma unroll
        for (int reg = 0; reg < 4; ++reg) {
            int gr = r0 + wave * 32 + mi * 16 + quad * 4 + reg;
            if (gr >= N) continue;
            float rsv = rsum[gr];
#pragma unroll
            for (int ni = 0; ni < 4; ++ni) {
                int gc = c0 + ni * 16 + l15;
                float o = acc[mi][ni][reg] + rsv * wr[ni] + bi[ni];
                o = fmaxf(o, 0.f);
                if (gc >= Cout) o = 0.f;
                ps[ni] += o; pq[ni] += o * o;
                if (gc < MAIN) {
                    if (gc < TOTW) outM[(size_t)gr * SPm + gc] = (f16)o;
                } else if (gc < TOTW) {
                    outT[(size_t)gr * 8 + (gc - MAIN)] = (f16)o;
                }
            }
        }
    }
    if (do_stats) {
#pragma unroll
        for (int ni = 0; ni < 4; ++ni) {
            int cl = ni * 16 + l15;
            atomicAdd(&s_sum[cl], ps[ni]);
            atomicAdd(&s_sq[cl], pq[ni]);
        }
        __syncthreads();
        if (t < 64 && c0 + t < Cout) {
            atomicAdd(&colsum[c0 + t], s_sum[t]);
            atomicAdd(&colsq[c0 + t], s_sq[t]);
        }
    }
}

// ---- layer-3 GEMM with fused mean-pool (register shuffle-reduce, tiny LDS) ----

__global__ __launch_bounds__(256) void k_gemm_pool(
    const f16* __restrict__ A, int SPa,
    const f16* __restrict__ Bt, int KP,
    const float* __restrict__ rsum, const float* __restrict__ wrow,
    const float* __restrict__ bias, const int* __restrict__ batch,
    float* __restrict__ pooled, int N, int Cout) {
    __shared__ f16 As[128][40];
    __shared__ int sbat[128];
    __shared__ float s_red[4][64];
    const int r0 = blockIdx.x * 128;
    const int c0 = blockIdx.y * 64;
    const int t = threadIdx.x;
    const int wave = t >> 6, lane = t & 63;
    const int l15 = lane & 15, quad = lane >> 4;

    if (t < 128) {
        int gr = r0 + t;
        sbat[t] = batch[(gr < N) ? gr : (N - 1)];
    }

    f32x4 zero4 = {0.f, 0.f, 0.f, 0.f};
    f32x4 acc[2][4];
#pragma unroll
    for (int mi = 0; mi < 2; ++mi)
#pragma unroll
        for (int ni = 0; ni < 4; ++ni) acc[mi][ni] = zero4;

    const int KT = KP >> 5;
    for (int kt = 0; kt < KT; ++kt) {
        int k0 = kt * 32;
        {
            int kcol = (t & 7) * 4;
            int rbase = t >> 3;
            int gk = k0 + kcol;
            bool kok = (gk + 4 <= SPa);
#pragma unroll
            for (int i = 0; i < 4; ++i) {
                int row = rbase + i * 32;
                int gr = r0 + row;
                ushort4 v = {0, 0, 0, 0};
                if (gr < N && kok)
                    v = *(const ushort4*)(A + (size_t)gr * SPa + gk);
                *(ushort4*)&As[row][kcol] = v;
            }
        }
        __syncthreads();
        half8 a0 = *(const half8*)&As[wave * 32 + l15][quad * 8];
        half8 a1 = *(const half8*)&As[wave * 32 + 16 + l15][quad * 8];
#pragma unroll
        for (int ni = 0; ni < 4; ++ni) {
            half8 b = *(const half8*)(Bt + (size_t)(c0 + ni * 16 + l15) * KP + k0 + quad * 8);
            acc[0][ni] = __builtin_amdgcn_mfma_f32_16x16x32_f16(a0, b, acc[0][ni], 0, 0, 0);
            acc[1][ni] = __builtin_amdgcn_mfma_f32_16x16x32_f16(a1, b, acc[1][ni], 0, 0, 0);
        }
        __syncthreads();
    }

    // ---- epilogue: relu(o) in registers, cache my 8 rows' graph ids ----
    float wr[4], bi[4];
#pragma unroll
    for (int ni = 0; ni < 4; ++ni) {
        int gc = c0 + ni * 16 + l15;
        wr[ni] = wrow[gc];
        bi[ni] = (gc < Cout) ? bias[gc] : 0.f;
    }
    int gid[8];
#pragma unroll
    for (int mi = 0; mi < 2; ++mi) {
#pragma unroll
        for (int reg = 0; reg < 4; ++reg) {
            int lrow = wave * 32 + mi * 16 + quad * 4 + reg;
            int gr = r0 + lrow;
            bool rok = (gr < N);
            float rsv = rok ? rsum[gr] : 0.f;
            gid[mi * 4 + reg] = sbat[lrow];
#pragma unroll
            for (int ni = 0; ni < 4; ++ni) {
                float o = acc[mi][ni][reg] + rsv * wr[ni] + bi[ni];
                o = fmaxf(o, 0.f);
                acc[mi][ni][reg] = rok ? o : 0.f;
            }
        }
    }

    // ---- segmented pool: per graph segment, masked reg sum -> quad shuffle
    //      -> cross-wave LDS combine -> one atomic per column ----
    const int g0 = sbat[0];
    const int gmax = sbat[127];
    for (int g = g0; g <= gmax; ++g) {
        float part[4] = {0.f, 0.f, 0.f, 0.f};
#pragma unroll
        for (int mi = 0; mi < 2; ++mi)
#pragma unroll
            for (int reg = 0; reg < 4; ++reg) {
                bool m = (gid[mi * 4 + reg] == g);
#pragma unroll
                for (int ni = 0; ni < 4; ++ni)
                    part[ni] += m ? acc[mi][ni][reg] : 0.f;
            }
#pragma unroll
        for (int ni = 0; ni < 4; ++ni) {
            part[ni] += __shfl_down(part[ni], 32);
            part[ni] += __shfl_down(part[ni], 16);
        }
        if (lane < 16) {
#pragma unroll
            for (int ni = 0; ni < 4; ++ni) s_red[wave][ni * 16 + lane] = part[ni];
        }
        __syncthreads();
        if (t < 64) {
            int gc = c0 + t;
            if (gc < Cout) {
                float v = s_red[0][t] + s_red[1][t] + s_red[2][t] + s_red[3][t];
                if (v != 0.f) atomicAdd(&pooled[(size_t)g * Cout + gc], v);
            }
        }
        __syncthreads();
    }
}

// ---------------- head MLP ----------------

__global__ void k_mlp(const float* __restrict__ pooled, const int* __restrict__ gstart,
                      const int* __restrict__ gend,
                      const float* __restrict__ Wl1, const float* __restrict__ bl1,
                      const float* __restrict__ Wl2, const float* __restrict__ bl2,
                      float* __restrict__ out, int C) {
    __shared__ float p[199];
    __shared__ float t1[49];
    int g = blockIdx.x;
    int cnt = gend[g] - gstart[g];
    float inv = 1.f / (float)(cnt > 1 ? cnt : 1);
    for (int k = threadIdx.x; k < C; k += blockDim.x) p[k] = pooled[g * C + k] * inv;
    __syncthreads();
    if (threadIdx.x < 49) {
        float acc = bl1[threadIdx.x];
        for (int k = 0; k < C; ++k) acc += p[k] * Wl1[k * 49 + threadIdx.x];
        t1[threadIdx.x] = acc;
    }
    __syncthreads();
    if (threadIdx.x < 2) {
        float acc = bl2[threadIdx.x];
        for (int k = 0; k < 49; ++k) acc += t1[k] * Wl2[k * 2 + threadIdx.x];
        out[g * 2 + threadIdx.x] = acc;
    }
}

// ---------------- launch ----------------

extern "C" void kernel_launch(void* const* d_in, const int* in_sizes, int n_in,
                              void* d_out, int out_size, void* d_ws, size_t ws_size,
                              hipStream_t stream) {
    const float* x     = (const float*)d_in[0];
    const int*   ei    = (const int*)d_in[1];
    const int*   batch = (const int*)d_in[2];
    const float* bn0g = (const float*)d_in[3];
    const float* bn0b = (const float*)d_in[4];
    const float* bn1g = (const float*)d_in[5];
    const float* bn1b = (const float*)d_in[6];
    const float* bn2g = (const float*)d_in[7];
    const float* bn2b = (const float*)d_in[8];
    const float* W1  = (const float*)d_in[9];
    const float* b1  = (const float*)d_in[10];
    const float* W2  = (const float*)d_in[11];
    const float* b2  = (const float*)d_in[12];
    const float* W3  = (const float*)d_in[13];
    const float* b3  = (const float*)d_in[14];
    const float* Wl1 = (const float*)d_in[15];
    const float* bl1 = (const float*)d_in[16];
    const float* Wl2 = (const float*)d_in[17];
    const float* bl2 = (const float*)d_in[18];

    const int N = in_sizes[0] / 7;
    const int E = in_sizes[1] / 2;
    const int EN = E + N;
    const int G = out_size / 2;
    const int NB = (N + 255) / 256;
    const int NBK = (N + 255) / 256;        // buckets of 256 nodes
    const int NBIN = (EN + BIN_CH - 1) / BIN_CH;

    const int* src = ei;
    const int* dst = ei + E;

    char* w = (char*)d_ws;
    auto alloc = [&](size_t bytes) -> void* {
        void* p = (void*)w;
        w += ((bytes + 255) / 256) * 256;
        return p;
    };
    // Split H-tables:
    //   H1m [N,64]h | H1t [N,8]h | H2m [N,128]h | H2t [N,8]h
    size_t szH1m = (size_t)N * 64 * sizeof(__half);
    size_t szH1t = (size_t)N * 8 * sizeof(__half);
    size_t szH2m = (size_t)N * 128 * sizeof(__half);
    size_t szH2t = (size_t)N * 8 * sizeof(__half);
    char* regA = (char*)alloc(szH1m + szH1t + szH2m + szH2t);
    __half* H1m = (__half*)regA;
    __half* H1t = (__half*)(regA + szH1m);
    __half* H2m = (__half*)(regA + szH1m + szH1t);
    __half* H2t = (__half*)(regA + szH1m + szH1t + szH2m);

    __half* bufG = (__half*)alloc((size_t)N * 136 * sizeof(__half));  // gather outputs (max width)
    f16*    wp   = (f16*)  alloc((size_t)256 * 160 * sizeof(f16));
    float*  wrow = (float*)alloc(256 * sizeof(float));
    __half* xp   = (__half*)alloc((size_t)N * 8 * sizeof(__half));
    float* disq  = (float*)alloc((size_t)N * sizeof(float));
    float* rsum  = (float*)alloc((size_t)N * sizeof(float));
    int*   deg   = (int*)  alloc((size_t)N * sizeof(int));
    int*   rs    = (int*)  alloc((size_t)N * sizeof(int));
    int*   binned= (int*)  alloc((size_t)NBK * BCAP * sizeof(int));
    int*   csr_s = (int*)  alloc((size_t)NBK * BCAP * sizeof(int));
    float* csr_w = (float*)alloc((size_t)NBK * BCAP * sizeof(float));
    // contiguous zero-init region: 6 stat arrays (1KB each) + gcur (2KB) + pooled
    float* colsum0 = (float*)alloc(256 * sizeof(float));
    float* colsq0  = (float*)alloc(256 * sizeof(float));
    float* colsumA = (float*)alloc(256 * sizeof(float));
    float* colsqA  = (float*)alloc(256 * sizeof(float));
    float* colsumB = (float*)alloc(256 * sizeof(float));
    float* colsqB  = (float*)alloc(256 * sizeof(float));
    int*   gcur    = (int*)  alloc(512 * sizeof(int));
    float* pooled  = (float*)alloc((size_t)G * 199 * sizeof(float));
    int*   gstart  = (int*)  alloc((size_t)G * sizeof(int));
    int*   gend    = (int*)  alloc((size_t)G * sizeof(int));

    size_t zbytes = 6 * 1024 + 2048 + (((size_t)G * 199 * sizeof(float) + 255) / 256) * 256;
    hipMemsetAsync(colsum0, 0, zbytes, stream);   // stats + gcur + pooled, one node

    // ---- binned CSR build (single pass, fixed-capacity buckets) ----
    k_bin<<<NBIN, 256, 0, stream>>>(src, dst, E, EN, NBK, gcur, binned);
    k_bucket<<<NBK, 256, 0, stream>>>(binned, gcur, N, deg, rs, csr_s, disq);
    k_wfill<<<(N + 3) / 4, 256, 0, stream>>>(rs, deg, csr_s, disq, csr_w, N);

    const int GB = (N + 127) / 128;

    // ---- layer 1 ----
    k_padx_stats<<<NB, 256, 0, stream>>>(x, xp, N, colsum0, colsq0, batch, gstart, gend);
    k_prep<<<128, 256, 0, stream>>>(colsum0, colsq0, bn0g, bn0b, 1.f / (float)N,
                                    W1, 7, 71, 32, wp, wrow);
    k_gather8<<<(N + 255) / 256, 256, 0, stream>>>(xp, csr_s, csr_w, rs, deg, bufG, rsum, N);
    {
        dim3 grid(GB, 2);
        k_gemm_mfma<<<grid, 256, 0, stream>>>((const f16*)bufG, 8, wp, 32, rsum, wrow, b1,
                                              (f16*)H1m, 64, 64, (f16*)H1t, 72,
                                              colsumA, colsqA, 1, N, 71);
    }
    // ---- layer 2 ----
    k_prep<<<192, 256, 0, stream>>>(colsumA, colsqA, bn1g, bn1b, 1.f / (float)N,
                                    W2, 71, 135, 96, wp, wrow);
    k_gather_w<<<(N + 31) / 32, 256, 0, stream>>>(H1m, 64, 3,
                                                  rs, deg, csr_s, csr_w, bufG, 72, N);
    k_gather_tail<<<(N + 255) / 256, 256, 0, stream>>>(H1t, csr_s, csr_w, rs, deg,
                                                       bufG, 72, 64, N);
    {
        dim3 grid(GB, 3);
        k_gemm_mfma<<<grid, 256, 0, stream>>>((const f16*)bufG, 72, wp, 96, rsum, wrow, b2,
                                              (f16*)H2m, 128, 128, (f16*)H2t, 136,
                                              colsumB, colsqB, 1, N, 135);
    }
    // ---- layer 3 (GEMM fused with mean-pool; no H3) ----
    k_prep<<<256, 256, 0, stream>>>(colsumB, colsqB, bn2g, bn2b, 1.f / (float)N,
                                    W3, 135, 199, 160, wp, wrow);
    k_gather_w<<<(N + 15) / 16, 256, 0, stream>>>(H2m, 128, 4,
                                                  rs, deg, csr_s, csr_w, bufG, 136, N);
    k_gather_tail<<<(N + 255) / 256, 256, 0, stream>>>(H2t, csr_s, csr_w, rs, deg,
                                                       bufG, 136, 128, N);
    {
        dim3 grid(GB, 4);
        k_gemm_pool<<<grid, 256, 0, stream>>>((const f16*)bufG, 136, wp, 160, rsum, wrow, b3,
                                              batch, pooled, N, 199);
    }

    // ---- head ----
    k_mlp<<<G, 64, 0, stream>>>(pooled, gstart, gend, Wl1, bl1, Wl2, bl2, (float*)d_out, 199);
}

// Round 5
// 489.878 us; speedup vs baseline: 1.2256x; 1.0299x over previous
//
#include <hip/hip_runtime.h>
#include <hip/hip_fp16.h>

#define EPSV 1e-5f
#define BIN_CH 4096
#define BCAP 8192   // fixed bucket capacity (mean ~4348, sigma ~66 for uniform random)

typedef _Float16 f16;
typedef f16 half8 __attribute__((ext_vector_type(8)));
typedef float f32x4 __attribute__((ext_vector_type(4)));

// ---------------- binned CSR construction (single-pass, fixed-capacity buckets) ----

__global__ __launch_bounds__(256) void k_bin(const int* __restrict__ src,
                                             const int* __restrict__ dst, int E, int EN,
                                             int NBK, int* __restrict__ gcur,
                                             int* __restrict__ binned) {
    __shared__ int cnt[512];
    __shared__ int base[512];
    for (int b = threadIdx.x; b < 512; b += 256) cnt[b] = 0;
    __syncthreads();
    int i0 = blockIdx.x * BIN_CH;
    int i1 = i0 + BIN_CH; if (i1 > EN) i1 = EN;
    for (int i = i0 + threadIdx.x; i < i1; i += 256) {
        int d = (i < E) ? dst[i] : (i - E);
        atomicAdd(&cnt[d >> 8], 1);
    }
    __syncthreads();
    for (int b = threadIdx.x; b < NBK; b += 256)
        if (cnt[b]) base[b] = b * BCAP + atomicAdd(&gcur[b], cnt[b]);
    __syncthreads();
    for (int i = i0 + threadIdx.x; i < i1; i += 256) {
        int s, d;
        if (i < E) { s = src[i]; d = dst[i]; }
        else       { s = i - E; d = s; }
        int pos = atomicAdd(&base[d >> 8], 1);
        binned[pos] = s | ((d & 255) << 24);   // src < 2^24
    }
}

__global__ __launch_bounds__(256) void k_bucket(const int* __restrict__ binned,
                                                const int* __restrict__ gcur, int N,
                                                int* __restrict__ deg, int* __restrict__ rs,
                                                int* __restrict__ csr_s,
                                                float* __restrict__ disq) {
    __shared__ int deg_l[256];
    __shared__ int sc[256];
    __shared__ int cur_l[256];
    int b = blockIdx.x;
    int t = threadIdx.x;
    int start = b * BCAP, end = start + gcur[b];
    deg_l[t] = 0;
    __syncthreads();
    for (int i = start + t; i < end; i += 256)
        atomicAdd(&deg_l[((unsigned)binned[i]) >> 24], 1);
    __syncthreads();
    sc[t] = deg_l[t];
    __syncthreads();
    for (int off = 1; off < 256; off <<= 1) {
        int v = (t >= off) ? sc[t - off] : 0;
        __syncthreads();
        sc[t] += v;
        __syncthreads();
    }
    int rs_l = sc[t] - deg_l[t];
    int n = b * 256 + t;
    if (n < N) {
        deg[n] = deg_l[t];
        rs[n] = start + rs_l;
        disq[n] = rsqrtf((float)(deg_l[t] > 0 ? deg_l[t] : 1));
    }
    cur_l[t] = start + rs_l;
    __syncthreads();
    for (int i = start + t; i < end; i += 256) {
        int p = binned[i];
        int loc = ((unsigned)p) >> 24;
        int idx = atomicAdd(&cur_l[loc], 1);
        csr_s[idx] = p & 0xFFFFFF;
    }
}

__global__ __launch_bounds__(256) void k_wfill(const int* __restrict__ rs,
                                               const int* __restrict__ deg,
                                               const int* __restrict__ csr_s,
                                               const float* __restrict__ disq,
                                               float* __restrict__ csr_w, int N) {
    int wave = threadIdx.x >> 6, lane = threadIdx.x & 63;
    int n = blockIdx.x * 4 + wave;
    if (n >= N) return;
    int e0 = rs[n], dg = deg[n];
    float dn = disq[n];
    for (int j = lane; j < dg; j += 64) {
        int s = csr_s[e0 + j];
        csr_w[e0 + j] = disq[s] * dn;
    }
}

// ---- fused per-layer prep: scale/shift from raw sums + Wp_t + wrow ----

__global__ __launch_bounds__(256) void k_prep(
    const float* __restrict__ colsum, const float* __restrict__ colsq,
    const float* __restrict__ g, const float* __restrict__ b, float invN,
    const float* __restrict__ W, int Cin, int Cout, int KP,
    f16* __restrict__ Wp, float* __restrict__ wrow) {
    __shared__ float lsc[192];
    __shared__ float lsh[192];
    __shared__ float red[4];
    int t = threadIdx.x;
    int c = blockIdx.x;
    if (t < KP) {
        float scv = 0.f, shv = 0.f;
        if (t < Cin) {
            float m = colsum[t] * invN;
            float v = colsq[t] * invN - m * m;
            float rstd = rsqrtf(fmaxf(v, 0.f) + EPSV);
            scv = rstd * g[t];
            shv = b[t] - m * scv;
        }
        lsc[t] = scv; lsh[t] = shv;
    }
    __syncthreads();
    float part = 0.f;
    if (t < KP) {
        float wv = (t < Cin && c < Cout) ? W[(size_t)t * Cout + c] : 0.f;
        Wp[(size_t)c * KP + t] = (f16)(lsc[t] * wv);
        part = lsh[t] * wv;
    }
    for (int off = 32; off > 0; off >>= 1) part += __shfl_down(part, off);
    int lane = t & 63, wid = t >> 6;
    if (lane == 0) red[wid] = part;
    __syncthreads();
    if (t == 0) wrow[c] = red[0] + red[1] + red[2] + red[3];
}

// -- pad x [N,7] -> xp [N,8] fp16 + BN stats (direct atomics) + graph bounds --

__global__ __launch_bounds__(256) void k_padx_stats(const float* __restrict__ x,
                                                    __half* __restrict__ xp, int N,
                                                    float* __restrict__ colsum,
                                                    float* __restrict__ colsq,
                                                    const int* __restrict__ batch,
                                                    int* __restrict__ gstart,
                                                    int* __restrict__ gend) {
    __shared__ float ls[16];
    int t = threadIdx.x;
    int n = blockIdx.x * 256 + t;
    int lane = t & 63;
    if (t < 16) ls[t] = 0.f;
    __syncthreads();
    float v[7] = {0.f, 0.f, 0.f, 0.f, 0.f, 0.f, 0.f};
    if (n < N) {
#pragma unroll
        for (int j = 0; j < 7; ++j) v[j] = x[(size_t)n * 7 + j];
        __half h[8];
#pragma unroll
        for (int j = 0; j < 7; ++j) h[j] = __float2half(v[j]);
        h[7] = __float2half(0.f);
        *(float4*)(xp + (size_t)n * 8) = *(float4*)h;
        // graph segment bounds (batch sorted)
        int g = batch[n];
        int gp = (n == 0) ? -1 : batch[n - 1];
        if (gp != g) gstart[g] = n;
        int gn = (n == N - 1) ? -1 : batch[n + 1];
        if (gn != g) gend[g] = n + 1;
    }
#pragma unroll
    for (int j = 0; j < 7; ++j) {
        float s = v[j];
        float q = v[j] * v[j];
        for (int off = 32; off > 0; off >>= 1) {
            s += __shfl_down(s, off);
            q += __shfl_down(q, off);
        }
        if (lane == 0) {
            atomicAdd(&ls[j], s);
            atomicAdd(&ls[8 + j], q);
        }
    }
    __syncthreads();
    if (t < 8)               atomicAdd(&colsum[t], ls[t]);
    else if (t < 16)         atomicAdd(&colsq[t - 8], ls[t]);
}

// ---------------- layer-1 gather: G = S . xp (L2-resident 16B rows) ----------------

__global__ void k_gather8(const __half* __restrict__ xp, const int* __restrict__ csr_s,
                          const float* __restrict__ csr_w,
                          const int* __restrict__ rs, const int* __restrict__ deg,
                          __half* __restrict__ out, float* __restrict__ rsum, int N) {
    int n = blockIdx.x * blockDim.x + threadIdx.x;
    if (n >= N) return;
    int e0 = rs[n], eend = e0 + deg[n];
    float a0 = 0.f, a1 = 0.f, a2 = 0.f, a3 = 0.f, a4 = 0.f, a5 = 0.f, a6 = 0.f, a7 = 0.f;
    float ws = 0.f;
    for (int e = e0; e < eend; ++e) {
        int s = csr_s[e];
        float w = csr_w[e];
        ws += w;
        float4 r = *(const float4*)(xp + (size_t)s * 8);
        const __half2* hh = (const __half2*)&r;
        float2 q0 = __half22float2(hh[0]);
        float2 q1 = __half22float2(hh[1]);
        float2 q2 = __half22float2(hh[2]);
        float2 q3 = __half22float2(hh[3]);
        a0 = fmaf(w, q0.x, a0); a1 = fmaf(w, q0.y, a1);
        a2 = fmaf(w, q1.x, a2); a3 = fmaf(w, q1.y, a3);
        a4 = fmaf(w, q2.x, a4); a5 = fmaf(w, q2.y, a5);
        a6 = fmaf(w, q3.x, a6); a7 = fmaf(w, q3.y, a7);
    }
    rsum[n] = ws;
    __half h[8];
    h[0] = __float2half(a0); h[1] = __float2half(a1);
    h[2] = __float2half(a2); h[3] = __float2half(a3);
    h[4] = __float2half(a4); h[5] = __float2half(a5);
    h[6] = __float2half(a6); h[7] = __float2half(a7);
    *(float4*)(out + (size_t)n * 8) = *(float4*)h;
}

// ------------- layer-1 MFMA GEMM (unchanged): split store + stats -------------

__global__ __launch_bounds__(256) void k_gemm_mfma(
    const f16* __restrict__ A, int SPa,
    const f16* __restrict__ Bt, int KP,
    const float* __restrict__ rsum, const float* __restrict__ wrow,
    const float* __restrict__ bias,
    f16* __restrict__ outM, int SPm, int MAIN, f16* __restrict__ outT, int TOTW,
    float* __restrict__ colsum, float* __restrict__ colsq, int do_stats,
    int N, int Cout) {
    __shared__ f16 As[128][40];
    __shared__ float s_sum[64];
    __shared__ float s_sq[64];
    const int r0 = blockIdx.x * 128;
    const int c0 = blockIdx.y * 64;
    const int t = threadIdx.x;
    const int wave = t >> 6, lane = t & 63;
    const int l15 = lane & 15, quad = lane >> 4;

    if (t < 64) { s_sum[t] = 0.f; s_sq[t] = 0.f; }

    f32x4 zero4 = {0.f, 0.f, 0.f, 0.f};
    f32x4 acc[2][4];
#pragma unroll
    for (int mi = 0; mi < 2; ++mi)
#pragma unroll
        for (int ni = 0; ni < 4; ++ni) acc[mi][ni] = zero4;

    const int KT = KP >> 5;
    for (int kt = 0; kt < KT; ++kt) {
        int k0 = kt * 32;
        {
            int kcol = (t & 7) * 4;
            int rbase = t >> 3;
            int gk = k0 + kcol;
            bool kok = (gk + 4 <= SPa);
#pragma unroll
            for (int i = 0; i < 4; ++i) {
                int row = rbase + i * 32;
                int gr = r0 + row;
                ushort4 v = {0, 0, 0, 0};
                if (gr < N && kok)
                    v = *(const ushort4*)(A + (size_t)gr * SPa + gk);
                *(ushort4*)&As[row][kcol] = v;
            }
        }
        __syncthreads();
        half8 a0 = *(const half8*)&As[wave * 32 + l15][quad * 8];
        half8 a1 = *(const half8*)&As[wave * 32 + 16 + l15][quad * 8];
#pragma unroll
        for (int ni = 0; ni < 4; ++ni) {
            half8 b = *(const half8*)(Bt + (size_t)(c0 + ni * 16 + l15) * KP + k0 + quad * 8);
            acc[0][ni] = __builtin_amdgcn_mfma_f32_16x16x32_f16(a0, b, acc[0][ni], 0, 0, 0);
            acc[1][ni] = __builtin_amdgcn_mfma_f32_16x16x32_f16(a1, b, acc[1][ni], 0, 0, 0);
        }
        __syncthreads();
    }

    float wr[4], bi[4];
#pragma unroll
    for (int ni = 0; ni < 4; ++ni) {
        int gc = c0 + ni * 16 + l15;
        wr[ni] = wrow[gc];
        bi[ni] = (gc < Cout) ? bias[gc] : 0.f;
    }
    float ps[4] = {}, pq[4] = {};
#pragma unroll
    for (int mi = 0; mi < 2; ++mi) {
#pragma unroll
        for (int reg = 0; reg < 4; ++reg) {
            int gr = r0 + wave * 32 + mi * 16 + quad * 4 + reg;
            if (gr >= N) continue;
            float rsv = rsum[gr];
#pragma unroll
            for (int ni = 0; ni < 4; ++ni) {
                int gc = c0 + ni * 16 + l15;
                float o = acc[mi][ni][reg] + rsv * wr[ni] + bi[ni];
                o = fmaxf(o, 0.f);
                if (gc >= Cout) o = 0.f;
                ps[ni] += o; pq[ni] += o * o;
                if (gc < MAIN) {
                    if (gc < TOTW) outM[(size_t)gr * SPm + gc] = (f16)o;
                } else if (gc < TOTW) {
                    outT[(size_t)gr * 8 + (gc - MAIN)] = (f16)o;
                }
            }
        }
    }
    if (do_stats) {
#pragma unroll
        for (int ni = 0; ni < 4; ++ni) {
            int cl = ni * 16 + l15;
            atomicAdd(&s_sum[cl], ps[ni]);
            atomicAdd(&s_sq[cl], pq[ni]);
        }
        __syncthreads();
        if (t < 64 && c0 + t < Cout) {
            atomicAdd(&colsum[c0 + t], s_sum[t]);
            atomicAdd(&colsq[c0 + t], s_sq[t]);
        }
    }
}

// helper: 8-half fma accumulate from a float4-of-halves
__device__ __forceinline__ void fma8(float* acc, float w, float4 r) {
    float2 q0 = __half22float2(((const __half2*)&r)[0]);
    float2 q1 = __half22float2(((const __half2*)&r)[1]);
    float2 q2 = __half22float2(((const __half2*)&r)[2]);
    float2 q3 = __half22float2(((const __half2*)&r)[3]);
    acc[0] = fmaf(w, q0.x, acc[0]); acc[1] = fmaf(w, q0.y, acc[1]);
    acc[2] = fmaf(w, q1.x, acc[2]); acc[3] = fmaf(w, q1.y, acc[3]);
    acc[4] = fmaf(w, q2.x, acc[4]); acc[5] = fmaf(w, q2.y, acc[5]);
    acc[6] = fmaf(w, q3.x, acc[6]); acc[7] = fmaf(w, q3.y, acc[7]);
}

// ==== fused layer-2: gather(H1m/H1t) -> LDS -> GEMM(3 col tiles) -> H2 + stats ====

__global__ __launch_bounds__(256) void k_fused2(
    const __half* __restrict__ Am, const __half* __restrict__ At,
    const f16* __restrict__ Bt,
    const int* __restrict__ rs, const int* __restrict__ deg,
    const int* __restrict__ csr_s, const float* __restrict__ csr_w,
    const float* __restrict__ rsum, const float* __restrict__ wrow,
    const float* __restrict__ bias,
    f16* __restrict__ outM, f16* __restrict__ outT,
    float* __restrict__ colsum, float* __restrict__ colsq, int N) {
    const int KP = 96, ASW = 104, SPM = 64, COUT = 135;
    __shared__ f16 As[128][104];
    __shared__ float s_red[4][64];
    __shared__ float s_red2[4][64];
    const int r0 = blockIdx.x * 128;
    const int t = threadIdx.x;
    const int wave = t >> 6, lane = t & 63;
    const int l15 = lane & 15, quad = lane >> 4;

    {   // zero As: covers K-pad cols [72,96) and rows >= N
        float4 z = {0.f, 0.f, 0.f, 0.f};
        for (int i = t; i < 128 * ASW / 8; i += 256) ((float4*)As)[i] = z;
    }
    __syncthreads();

    // ---- gather main (64 cols): 8 chunks x 8 nodes/pass, 4 passes/wave ----
    {
        const int sub = lane >> 3, lsub = lane & 7;
        const __half* gb = Am + lsub * 8;
        for (int pass = 0; pass < 4; ++pass) {
            int lrow = wave * 32 + pass * 8 + sub;
            int n = r0 + lrow;
            float acc[8] = {};
            if (n < N) {
                int e0 = rs[n], eend = e0 + deg[n];
                int e = e0;
                for (; e + 8 <= eend; e += 8) {
                    int s[8]; float wv[8]; float4 r[8];
#pragma unroll
                    for (int i = 0; i < 8; ++i) { s[i] = csr_s[e + i]; wv[i] = csr_w[e + i]; }
#pragma unroll
                    for (int i = 0; i < 8; ++i) r[i] = *(const float4*)(gb + (size_t)s[i] * SPM);
#pragma unroll
                    for (int i = 0; i < 8; ++i) fma8(acc, wv[i], r[i]);
                }
                for (; e + 4 <= eend; e += 4) {
                    int s[4]; float wv[4]; float4 r[4];
#pragma unroll
                    for (int i = 0; i < 4; ++i) { s[i] = csr_s[e + i]; wv[i] = csr_w[e + i]; }
#pragma unroll
                    for (int i = 0; i < 4; ++i) r[i] = *(const float4*)(gb + (size_t)s[i] * SPM);
#pragma unroll
                    for (int i = 0; i < 4; ++i) fma8(acc, wv[i], r[i]);
                }
                for (; e < eend; ++e)
                    fma8(acc, csr_w[e], *(const float4*)(gb + (size_t)csr_s[e] * SPM));
            }
            __half2 h[4];
            h[0] = __floats2half2_rn(acc[0], acc[1]);
            h[1] = __floats2half2_rn(acc[2], acc[3]);
            h[2] = __floats2half2_rn(acc[4], acc[5]);
            h[3] = __floats2half2_rn(acc[6], acc[7]);
            *(float4*)&As[lrow][lsub * 8] = *(float4*)h;
        }
    }
    // ---- gather tail (cols 64..72): 2 lanes/node over 32 nodes/wave ----
    {
        const int p = lane >> 1, half = lane & 1;
        int lrow = wave * 32 + p;
        int n = r0 + lrow;
        float acc[8] = {};
        if (n < N) {
            int eend = rs[n] + deg[n];
            int e = rs[n] + half;
            for (; e + 6 < eend; e += 8) {
                int s0 = csr_s[e], s1 = csr_s[e + 2], s2 = csr_s[e + 4], s3 = csr_s[e + 6];
                float w0 = csr_w[e], w1 = csr_w[e + 2], w2 = csr_w[e + 4], w3 = csr_w[e + 6];
                float4 r0_ = *(const float4*)(At + (size_t)s0 * 8);
                float4 r1_ = *(const float4*)(At + (size_t)s1 * 8);
                float4 r2_ = *(const float4*)(At + (size_t)s2 * 8);
                float4 r3_ = *(const float4*)(At + (size_t)s3 * 8);
                fma8(acc, w0, r0_); fma8(acc, w1, r1_);
                fma8(acc, w2, r2_); fma8(acc, w3, r3_);
            }
            for (; e < eend; e += 2)
                fma8(acc, csr_w[e], *(const float4*)(At + (size_t)csr_s[e] * 8));
        }
#pragma unroll
        for (int j = 0; j < 8; ++j) acc[j] += __shfl_xor(acc[j], 1);
        if (half == 0) {
            __half2 h[4];
            h[0] = __floats2half2_rn(acc[0], acc[1]);
            h[1] = __floats2half2_rn(acc[2], acc[3]);
            h[2] = __floats2half2_rn(acc[4], acc[5]);
            h[3] = __floats2half2_rn(acc[6], acc[7]);
            *(float4*)&As[lrow][64] = *(float4*)h;
        }
    }
    __syncthreads();

    // ---- GEMM over 3 column tiles (As resident; gather done once) ----
    for (int ct = 0; ct < 3; ++ct) {
        const int c0 = ct * 64;
        f32x4 zero4 = {0.f, 0.f, 0.f, 0.f};
        f32x4 acc2[2][4];
#pragma unroll
        for (int mi = 0; mi < 2; ++mi)
#pragma unroll
            for (int ni = 0; ni < 4; ++ni) acc2[mi][ni] = zero4;
#pragma unroll
        for (int kt = 0; kt < 3; ++kt) {
            int k0 = kt * 32;
            half8 a0 = *(const half8*)&As[wave * 32 + l15][k0 + quad * 8];
            half8 a1 = *(const half8*)&As[wave * 32 + 16 + l15][k0 + quad * 8];
#pragma unroll
            for (int ni = 0; ni < 4; ++ni) {
                half8 b = *(const half8*)(Bt + (size_t)(c0 + ni * 16 + l15) * KP + k0 + quad * 8);
                acc2[0][ni] = __builtin_amdgcn_mfma_f32_16x16x32_f16(a0, b, acc2[0][ni], 0, 0, 0);
                acc2[1][ni] = __builtin_amdgcn_mfma_f32_16x16x32_f16(a1, b, acc2[1][ni], 0, 0, 0);
            }
        }
        float wr[4], bi[4];
#pragma unroll
        for (int ni = 0; ni < 4; ++ni) {
            int gc = c0 + ni * 16 + l15;
            wr[ni] = wrow[gc];
            bi[ni] = (gc < COUT) ? bias[gc] : 0.f;
        }
        float ps[4] = {}, pq[4] = {};
#pragma unroll
        for (int mi = 0; mi < 2; ++mi) {
#pragma unroll
            for (int reg = 0; reg < 4; ++reg) {
                int gr = r0 + wave * 32 + mi * 16 + quad * 4 + reg;
                if (gr >= N) continue;
                float rsv = rsum[gr];
#pragma unroll
                for (int ni = 0; ni < 4; ++ni) {
                    int gc = c0 + ni * 16 + l15;
                    float o = acc2[mi][ni][reg] + rsv * wr[ni] + bi[ni];
                    o = fmaxf(o, 0.f);
                    if (gc >= COUT) o = 0.f;
                    ps[ni] += o; pq[ni] += o * o;
                    if (gc < 128)      outM[(size_t)gr * 128 + gc] = (f16)o;
                    else if (gc < 136) outT[(size_t)gr * 8 + (gc - 128)] = (f16)o;
                }
            }
        }
        // stats reduce: quad fold -> cross-wave LDS -> global atomics
#pragma unroll
        for (int ni = 0; ni < 4; ++ni) {
            ps[ni] += __shfl_down(ps[ni], 32); ps[ni] += __shfl_down(ps[ni], 16);
            pq[ni] += __shfl_down(pq[ni], 32); pq[ni] += __shfl_down(pq[ni], 16);
        }
        if (lane < 16) {
#pragma unroll
            for (int ni = 0; ni < 4; ++ni) {
                s_red[wave][ni * 16 + lane] = ps[ni];
                s_red2[wave][ni * 16 + lane] = pq[ni];
            }
        }
        __syncthreads();
        if (t < 64) {
            int gc = c0 + t;
            if (gc < COUT) {
                atomicAdd(&colsum[gc], s_red[0][t] + s_red[1][t] + s_red[2][t] + s_red[3][t]);
                atomicAdd(&colsq[gc], s_red2[0][t] + s_red2[1][t] + s_red2[2][t] + s_red2[3][t]);
            }
        }
        __syncthreads();
    }
}

// ==== fused layer-3: gather(H2m/H2t) -> LDS -> GEMM(4 col tiles) -> mean-pool ====

__global__ __launch_bounds__(256) void k_fused3(
    const __half* __restrict__ Am, const __half* __restrict__ At,
    const f16* __restrict__ Bt,
    const int* __restrict__ rs, const int* __restrict__ deg,
    const int* __restrict__ csr_s, const float* __restrict__ csr_w,
    const float* __restrict__ rsum, const float* __restrict__ wrow,
    const float* __restrict__ bias, const int* __restrict__ batch,
    float* __restrict__ pooled, int N) {
    const int KP = 160, ASW = 168, SPM = 128, COUT = 199;
    __shared__ f16 As[128][168];
    __shared__ int sbat[128];
    __shared__ float s_red[4][64];
    const int r0 = blockIdx.x * 128;
    const int t = threadIdx.x;
    const int wave = t >> 6, lane = t & 63;
    const int l15 = lane & 15, quad = lane >> 4;

    if (t < 128) {
        int gr = r0 + t;
        sbat[t] = batch[(gr < N) ? gr : (N - 1)];
    }
    {   // zero As: covers K-pad cols [136,160) and rows >= N
        float4 z = {0.f, 0.f, 0.f, 0.f};
        for (int i = t; i < 128 * ASW / 8; i += 256) ((float4*)As)[i] = z;
    }
    __syncthreads();

    // ---- gather main (128 cols): 16 chunks x 4 nodes/pass, 8 passes/wave ----
    {
        const int sub = lane >> 4, lsub = lane & 15;
        const __half* gb = Am + lsub * 8;
        for (int pass = 0; pass < 8; ++pass) {
            int lrow = wave * 32 + pass * 4 + sub;
            int n = r0 + lrow;
            float acc[8] = {};
            if (n < N) {
                int e0 = rs[n], eend = e0 + deg[n];
                int e = e0;
                for (; e + 8 <= eend; e += 8) {
                    int s[8]; float wv[8]; float4 r[8];
#pragma unroll
                    for (int i = 0; i < 8; ++i) { s[i] = csr_s[e + i]; wv[i] = csr_w[e + i]; }
#pragma unroll
                    for (int i = 0; i < 8; ++i) r[i] = *(const float4*)(gb + (size_t)s[i] * SPM);
#pragma unroll
                    for (int i = 0; i < 8; ++i) fma8(acc, wv[i], r[i]);
                }
                for (; e + 4 <= eend; e += 4) {
                    int s[4]; float wv[4]; float4 r[4];
#pragma unroll
                    for (int i = 0; i < 4; ++i) { s[i] = csr_s[e + i]; wv[i] = csr_w[e + i]; }
#pragma unroll
                    for (int i = 0; i < 4; ++i) r[i] = *(const float4*)(gb + (size_t)s[i] * SPM);
#pragma unroll
                    for (int i = 0; i < 4; ++i) fma8(acc, wv[i], r[i]);
                }
                for (; e < eend; ++e)
                    fma8(acc, csr_w[e], *(const float4*)(gb + (size_t)csr_s[e] * SPM));
            }
            __half2 h[4];
            h[0] = __floats2half2_rn(acc[0], acc[1]);
            h[1] = __floats2half2_rn(acc[2], acc[3]);
            h[2] = __floats2half2_rn(acc[4], acc[5]);
            h[3] = __floats2half2_rn(acc[6], acc[7]);
            *(float4*)&As[lrow][lsub * 8] = *(float4*)h;
        }
    }
    // ---- gather tail (cols 128..136): 2 lanes/node over 32 nodes/wave ----
    {
        const int p = lane >> 1, half = lane & 1;
        int lrow = wave * 32 + p;
        int n = r0 + lrow;
        float acc[8] = {};
        if (n < N) {
            int eend = rs[n] + deg[n];
            int e = rs[n] + half;
            for (; e + 6 < eend; e += 8) {
                int s0 = csr_s[e], s1 = csr_s[e + 2], s2 = csr_s[e + 4], s3 = csr_s[e + 6];
                float w0 = csr_w[e], w1 = csr_w[e + 2], w2 = csr_w[e + 4], w3 = csr_w[e + 6];
                float4 r0_ = *(const float4*)(At + (size_t)s0 * 8);
                float4 r1_ = *(const float4*)(At + (size_t)s1 * 8);
                float4 r2_ = *(const float4*)(At + (size_t)s2 * 8);
                float4 r3_ = *(const float4*)(At + (size_t)s3 * 8);
                fma8(acc, w0, r0_); fma8(acc, w1, r1_);
                fma8(acc, w2, r2_); fma8(acc, w3, r3_);
            }
            for (; e < eend; e += 2)
                fma8(acc, csr_w[e], *(const float4*)(At + (size_t)csr_s[e] * 8));
        }
#pragma unroll
        for (int j = 0; j < 8; ++j) acc[j] += __shfl_xor(acc[j], 1);
        if (half == 0) {
            __half2 h[4];
            h[0] = __floats2half2_rn(acc[0], acc[1]);
            h[1] = __floats2half2_rn(acc[2], acc[3]);
            h[2] = __floats2half2_rn(acc[4], acc[5]);
            h[3] = __floats2half2_rn(acc[6], acc[7]);
            *(float4*)&As[lrow][128] = *(float4*)h;
        }
    }
    __syncthreads();

    // hoist per-thread row info
    int gid[8]; float rsv8[8]; bool rok[8];
#pragma unroll
    for (int mi = 0; mi < 2; ++mi)
#pragma unroll
        for (int reg = 0; reg < 4; ++reg) {
            int lrow = wave * 32 + mi * 16 + quad * 4 + reg;
            int gr = r0 + lrow;
            int idx = mi * 4 + reg;
            gid[idx] = sbat[lrow];
            rok[idx] = (gr < N);
            rsv8[idx] = rok[idx] ? rsum[gr] : 0.f;
        }
    const int g0 = sbat[0];
    const int gmax = sbat[127];

    // ---- GEMM over 4 column tiles + fused mean-pool ----
    for (int ct = 0; ct < 4; ++ct) {
        const int c0 = ct * 64;
        f32x4 zero4 = {0.f, 0.f, 0.f, 0.f};
        f32x4 acc2[2][4];
#pragma unroll
        for (int mi = 0; mi < 2; ++mi)
#pragma unroll
            for (int ni = 0; ni < 4; ++ni) acc2[mi][ni] = zero4;
#pragma unroll
        for (int kt = 0; kt < 5; ++kt) {
            int k0 = kt * 32;
            half8 a0 = *(const half8*)&As[wave * 32 + l15][k0 + quad * 8];
            half8 a1 = *(const half8*)&As[wave * 32 + 16 + l15][k0 + quad * 8];
#pragma unroll
            for (int ni = 0; ni < 4; ++ni) {
                half8 b = *(const half8*)(Bt + (size_t)(c0 + ni * 16 + l15) * KP + k0 + quad * 8);
                acc2[0][ni] = __builtin_amdgcn_mfma_f32_16x16x32_f16(a0, b, acc2[0][ni], 0, 0, 0);
                acc2[1][ni] = __builtin_amdgcn_mfma_f32_16x16x32_f16(a1, b, acc2[1][ni], 0, 0, 0);
            }
        }
        float wr[4], bi[4];
#pragma unroll
        for (int ni = 0; ni < 4; ++ni) {
            int gc = c0 + ni * 16 + l15;
            wr[ni] = wrow[gc];
            bi[ni] = (gc < COUT) ? bias[gc] : 0.f;
        }
        // relu epilogue in registers (invalid rows and cols forced to 0)
#pragma unroll
        for (int mi = 0; mi < 2; ++mi)
#pragma unroll
            for (int reg = 0; reg < 4; ++reg) {
                int idx = mi * 4 + reg;
#pragma unroll
                for (int ni = 0; ni < 4; ++ni) {
                    int gc = c0 + ni * 16 + l15;
                    float o = acc2[mi][ni][reg] + rsv8[idx] * wr[ni] + bi[ni];
                    o = fmaxf(o, 0.f);
                    acc2[mi][ni][reg] = (rok[idx] && gc < COUT) ? o : 0.f;
                }
            }
        // segmented pool: masked reg sum -> quad shuffle -> cross-wave LDS -> atomic
        for (int g = g0; g <= gmax; ++g) {
            float part[4] = {0.f, 0.f, 0.f, 0.f};
#pragma unroll
            for (int mi = 0; mi < 2; ++mi)
#pragma unroll
                for (int reg = 0; reg < 4; ++reg) {
                    bool m = (gid[mi * 4 + reg] == g);
#pragma unroll
                    for (int ni = 0; ni < 4; ++ni)
                        part[ni] += m ? acc2[mi][ni][reg] : 0.f;
                }
#pragma unroll
            for (int ni = 0; ni < 4; ++ni) {
                part[ni] += __shfl_down(part[ni], 32);
                part[ni] += __shfl_down(part[ni], 16);
            }
            if (lane < 16) {
#pragma unroll
                for (int ni = 0; ni < 4; ++ni) s_red[wave][ni * 16 + lane] = part[ni];
            }
            __syncthreads();
            if (t < 64) {
                int gc = c0 + t;
                if (gc < COUT) {
                    float v = s_red[0][t] + s_red[1][t] + s_red[2][t] + s_red[3][t];
                    if (v != 0.f) atomicAdd(&pooled[(size_t)g * COUT + gc], v);
                }
            }
            __syncthreads();
        }
    }
}

// ---------------- head MLP ----------------

__global__ void k_mlp(const float* __restrict__ pooled, const int* __restrict__ gstart,
                      const int* __restrict__ gend,
                      const float* __restrict__ Wl1, const float* __restrict__ bl1,
                      const float* __restrict__ Wl2, const float* __restrict__ bl2,
                      float* __restrict__ out, int C) {
    __shared__ float p[199];
    __shared__ float t1[49];
    int g = blockIdx.x;
    int cnt = gend[g] - gstart[g];
    float inv = 1.f / (float)(cnt > 1 ? cnt : 1);
    for (int k = threadIdx.x; k < C; k += blockDim.x) p[k] = pooled[g * C + k] * inv;
    __syncthreads();
    if (threadIdx.x < 49) {
        float acc = bl1[threadIdx.x];
        for (int k = 0; k < C; ++k) acc += p[k] * Wl1[k * 49 + threadIdx.x];
        t1[threadIdx.x] = acc;
    }
    __syncthreads();
    if (threadIdx.x < 2) {
        float acc = bl2[threadIdx.x];
        for (int k = 0; k < 49; ++k) acc += t1[k] * Wl2[k * 2 + threadIdx.x];
        out[g * 2 + threadIdx.x] = acc;
    }
}

// ---------------- launch ----------------

extern "C" void kernel_launch(void* const* d_in, const int* in_sizes, int n_in,
                              void* d_out, int out_size, void* d_ws, size_t ws_size,
                              hipStream_t stream) {
    const float* x     = (const float*)d_in[0];
    const int*   ei    = (const int*)d_in[1];
    const int*   batch = (const int*)d_in[2];
    const float* bn0g = (const float*)d_in[3];
    const float* bn0b = (const float*)d_in[4];
    const float* bn1g = (const float*)d_in[5];
    const float* bn1b = (const float*)d_in[6];
    const float* bn2g = (const float*)d_in[7];
    const float* bn2b = (const float*)d_in[8];
    const float* W1  = (const float*)d_in[9];
    const float* b1  = (const float*)d_in[10];
    const float* W2  = (const float*)d_in[11];
    const float* b2  = (const float*)d_in[12];
    const float* W3  = (const float*)d_in[13];
    const float* b3  = (const float*)d_in[14];
    const float* Wl1 = (const float*)d_in[15];
    const float* bl1 = (const float*)d_in[16];
    const float* Wl2 = (const float*)d_in[17];
    const float* bl2 = (const float*)d_in[18];

    const int N = in_sizes[0] / 7;
    const int E = in_sizes[1] / 2;
    const int EN = E + N;
    const int G = out_size / 2;
    const int NB = (N + 255) / 256;
    const int NBK = (N + 255) / 256;        // buckets of 256 nodes
    const int NBIN = (EN + BIN_CH - 1) / BIN_CH;

    const int* src = ei;
    const int* dst = ei + E;

    char* w = (char*)d_ws;
    auto alloc = [&](size_t bytes) -> void* {
        void* p = (void*)w;
        w += ((bytes + 255) / 256) * 256;
        return p;
    };
    // Split H-tables:
    //   H1m [N,64]h | H1t [N,8]h | H2m [N,128]h | H2t [N,8]h
    size_t szH1m = (size_t)N * 64 * sizeof(__half);
    size_t szH1t = (size_t)N * 8 * sizeof(__half);
    size_t szH2m = (size_t)N * 128 * sizeof(__half);
    size_t szH2t = (size_t)N * 8 * sizeof(__half);
    char* regA = (char*)alloc(szH1m + szH1t + szH2m + szH2t);
    __half* H1m = (__half*)regA;
    __half* H1t = (__half*)(regA + szH1m);
    __half* H2m = (__half*)(regA + szH1m + szH1t);
    __half* H2t = (__half*)(regA + szH1m + szH1t + szH2m);

    __half* bufG = (__half*)alloc((size_t)N * 8 * sizeof(__half));   // layer-1 gather output
    f16*    wp   = (f16*)  alloc((size_t)256 * 160 * sizeof(f16));
    float*  wrow = (float*)alloc(256 * sizeof(float));
    __half* xp   = (__half*)alloc((size_t)N * 8 * sizeof(__half));
    float* disq  = (float*)alloc((size_t)N * sizeof(float));
    float* rsum  = (float*)alloc((size_t)N * sizeof(float));
    int*   deg   = (int*)  alloc((size_t)N * sizeof(int));
    int*   rs    = (int*)  alloc((size_t)N * sizeof(int));
    int*   binned= (int*)  alloc((size_t)NBK * BCAP * sizeof(int));
    int*   csr_s = (int*)  alloc((size_t)NBK * BCAP * sizeof(int));
    float* csr_w = (float*)alloc((size_t)NBK * BCAP * sizeof(float));
    // contiguous zero-init region: 6 stat arrays (1KB each) + gcur (2KB) + pooled
    float* colsum0 = (float*)alloc(256 * sizeof(float));
    float* colsq0  = (float*)alloc(256 * sizeof(float));
    float* colsumA = (float*)alloc(256 * sizeof(float));
    float* colsqA  = (float*)alloc(256 * sizeof(float));
    float* colsumB = (float*)alloc(256 * sizeof(float));
    float* colsqB  = (float*)alloc(256 * sizeof(float));
    int*   gcur    = (int*)  alloc(512 * sizeof(int));
    float* pooled  = (float*)alloc((size_t)G * 199 * sizeof(float));
    int*   gstart  = (int*)  alloc((size_t)G * sizeof(int));
    int*   gend    = (int*)  alloc((size_t)G * sizeof(int));

    size_t zbytes = 6 * 1024 + 2048 + (((size_t)G * 199 * sizeof(float) + 255) / 256) * 256;
    hipMemsetAsync(colsum0, 0, zbytes, stream);   // stats + gcur + pooled, one node

    // ---- binned CSR build (single pass, fixed-capacity buckets) ----
    k_bin<<<NBIN, 256, 0, stream>>>(src, dst, E, EN, NBK, gcur, binned);
    k_bucket<<<NBK, 256, 0, stream>>>(binned, gcur, N, deg, rs, csr_s, disq);
    k_wfill<<<(N + 3) / 4, 256, 0, stream>>>(rs, deg, csr_s, disq, csr_w, N);

    const int GB = (N + 127) / 128;

    // ---- layer 1 ----
    k_padx_stats<<<NB, 256, 0, stream>>>(x, xp, N, colsum0, colsq0, batch, gstart, gend);
    k_prep<<<128, 256, 0, stream>>>(colsum0, colsq0, bn0g, bn0b, 1.f / (float)N,
                                    W1, 7, 71, 32, wp, wrow);
    k_gather8<<<(N + 255) / 256, 256, 0, stream>>>(xp, csr_s, csr_w, rs, deg, bufG, rsum, N);
    {
        dim3 grid(GB, 2);
        k_gemm_mfma<<<grid, 256, 0, stream>>>((const f16*)bufG, 8, wp, 32, rsum, wrow, b1,
                                              (f16*)H1m, 64, 64, (f16*)H1t, 72,
                                              colsumA, colsqA, 1, N, 71);
    }
    // ---- layer 2 (fused gather+GEMM; no bufG) ----
    k_prep<<<192, 256, 0, stream>>>(colsumA, colsqA, bn1g, bn1b, 1.f / (float)N,
                                    W2, 71, 135, 96, wp, wrow);
    k_fused2<<<GB, 256, 0, stream>>>(H1m, H1t, wp, rs, deg, csr_s, csr_w,
                                     rsum, wrow, b2, (f16*)H2m, (f16*)H2t,
                                     colsumB, colsqB, N);
    // ---- layer 3 (fused gather+GEMM+mean-pool; no H3) ----
    k_prep<<<256, 256, 0, stream>>>(colsumB, colsqB, bn2g, bn2b, 1.f / (float)N,
                                    W3, 135, 199, 160, wp, wrow);
    k_fused3<<<GB, 256, 0, stream>>>(H2m, H2t, wp, rs, deg, csr_s, csr_w,
                                     rsum, wrow, b3, batch, pooled, N);

    // ---- head ----
    k_mlp<<<G, 64, 0, stream>>>(pooled, gstart, gend, Wl1, bl1, Wl2, bl2, (float*)d_out, 199);
}

// Round 6
// 459.362 us; speedup vs baseline: 1.3070x; 1.0664x over previous
//
#include <hip/hip_runtime.h>
#include <hip/hip_fp16.h>

#define EPSV 1e-5f
#define BIN_CH 4096
#define BCAP 8192   // fixed bucket capacity (mean ~4348, sigma ~66 for uniform random)

typedef _Float16 f16;
typedef f16 half8 __attribute__((ext_vector_type(8)));
typedef float f32x4 __attribute__((ext_vector_type(4)));

// ---------------- binned CSR construction (single-pass, fixed-capacity buckets) ----

__global__ __launch_bounds__(256) void k_bin(const int* __restrict__ src,
                                             const int* __restrict__ dst, int E, int EN,
                                             int NBK, int* __restrict__ gcur,
                                             int* __restrict__ binned) {
    __shared__ int cnt[512];
    __shared__ int base[512];
    for (int b = threadIdx.x; b < 512; b += 256) cnt[b] = 0;
    __syncthreads();
    int i0 = blockIdx.x * BIN_CH;
    int i1 = i0 + BIN_CH; if (i1 > EN) i1 = EN;
    for (int i = i0 + threadIdx.x; i < i1; i += 256) {
        int d = (i < E) ? dst[i] : (i - E);
        atomicAdd(&cnt[d >> 8], 1);
    }
    __syncthreads();
    for (int b = threadIdx.x; b < NBK; b += 256)
        if (cnt[b]) base[b] = b * BCAP + atomicAdd(&gcur[b], cnt[b]);
    __syncthreads();
    for (int i = i0 + threadIdx.x; i < i1; i += 256) {
        int s, d;
        if (i < E) { s = src[i]; d = dst[i]; }
        else       { s = i - E; d = s; }
        int pos = atomicAdd(&base[d >> 8], 1);
        binned[pos] = s | ((d & 255) << 24);   // src < 2^24
    }
}

__global__ __launch_bounds__(256) void k_bucket(const int* __restrict__ binned,
                                                const int* __restrict__ gcur, int N,
                                                int* __restrict__ deg, int* __restrict__ rs,
                                                int* __restrict__ csr_s,
                                                float* __restrict__ disq) {
    __shared__ int deg_l[256];
    __shared__ int sc[256];
    __shared__ int cur_l[256];
    int b = blockIdx.x;
    int t = threadIdx.x;
    int start = b * BCAP, end = start + gcur[b];
    deg_l[t] = 0;
    __syncthreads();
    for (int i = start + t; i < end; i += 256)
        atomicAdd(&deg_l[((unsigned)binned[i]) >> 24], 1);
    __syncthreads();
    sc[t] = deg_l[t];
    __syncthreads();
    for (int off = 1; off < 256; off <<= 1) {
        int v = (t >= off) ? sc[t - off] : 0;
        __syncthreads();
        sc[t] += v;
        __syncthreads();
    }
    int rs_l = sc[t] - deg_l[t];
    int n = b * 256 + t;
    if (n < N) {
        deg[n] = deg_l[t];
        rs[n] = start + rs_l;
        disq[n] = rsqrtf((float)(deg_l[t] > 0 ? deg_l[t] : 1));
    }
    cur_l[t] = start + rs_l;
    __syncthreads();
    for (int i = start + t; i < end; i += 256) {
        int p = binned[i];
        int loc = ((unsigned)p) >> 24;
        int idx = atomicAdd(&cur_l[loc], 1);
        csr_s[idx] = p & 0xFFFFFF;
    }
}

__global__ __launch_bounds__(256) void k_wfill(const int* __restrict__ rs,
                                               const int* __restrict__ deg,
                                               const int* __restrict__ csr_s,
                                               const float* __restrict__ disq,
                                               float* __restrict__ csr_w, int N) {
    int wave = threadIdx.x >> 6, lane = threadIdx.x & 63;
    int n = blockIdx.x * 4 + wave;
    if (n >= N) return;
    int e0 = rs[n], dg = deg[n];
    float dn = disq[n];
    for (int j = lane; j < dg; j += 64) {
        int s = csr_s[e0 + j];
        csr_w[e0 + j] = disq[s] * dn;
    }
}

// ---- fused per-layer prep: scale/shift from raw sums + Wp_t + wrow ----

__global__ __launch_bounds__(256) void k_prep(
    const float* __restrict__ colsum, const float* __restrict__ colsq,
    const float* __restrict__ g, const float* __restrict__ b, float invN,
    const float* __restrict__ W, int Cin, int Cout, int KP,
    f16* __restrict__ Wp, float* __restrict__ wrow) {
    __shared__ float lsc[192];
    __shared__ float lsh[192];
    __shared__ float red[4];
    int t = threadIdx.x;
    int c = blockIdx.x;
    if (t < KP) {
        float scv = 0.f, shv = 0.f;
        if (t < Cin) {
            float m = colsum[t] * invN;
            float v = colsq[t] * invN - m * m;
            float rstd = rsqrtf(fmaxf(v, 0.f) + EPSV);
            scv = rstd * g[t];
            shv = b[t] - m * scv;
        }
        lsc[t] = scv; lsh[t] = shv;
    }
    __syncthreads();
    float part = 0.f;
    if (t < KP) {
        float wv = (t < Cin && c < Cout) ? W[(size_t)t * Cout + c] : 0.f;
        Wp[(size_t)c * KP + t] = (f16)(lsc[t] * wv);
        part = lsh[t] * wv;
    }
    for (int off = 32; off > 0; off >>= 1) part += __shfl_down(part, off);
    int lane = t & 63, wid = t >> 6;
    if (lane == 0) red[wid] = part;
    __syncthreads();
    if (t == 0) wrow[c] = red[0] + red[1] + red[2] + red[3];
}

// -- pad x [N,7] -> xp [N,8] fp16 + BN stats (direct atomics) + graph bounds --

__global__ __launch_bounds__(256) void k_padx_stats(const float* __restrict__ x,
                                                    __half* __restrict__ xp, int N,
                                                    float* __restrict__ colsum,
                                                    float* __restrict__ colsq,
                                                    const int* __restrict__ batch,
                                                    int* __restrict__ gstart,
                                                    int* __restrict__ gend) {
    __shared__ float ls[16];
    int t = threadIdx.x;
    int n = blockIdx.x * 256 + t;
    int lane = t & 63;
    if (t < 16) ls[t] = 0.f;
    __syncthreads();
    float v[7] = {0.f, 0.f, 0.f, 0.f, 0.f, 0.f, 0.f};
    if (n < N) {
#pragma unroll
        for (int j = 0; j < 7; ++j) v[j] = x[(size_t)n * 7 + j];
        __half h[8];
#pragma unroll
        for (int j = 0; j < 7; ++j) h[j] = __float2half(v[j]);
        h[7] = __float2half(0.f);
        *(float4*)(xp + (size_t)n * 8) = *(float4*)h;
        // graph segment bounds (batch sorted)
        int g = batch[n];
        int gp = (n == 0) ? -1 : batch[n - 1];
        if (gp != g) gstart[g] = n;
        int gn = (n == N - 1) ? -1 : batch[n + 1];
        if (gn != g) gend[g] = n + 1;
    }
#pragma unroll
    for (int j = 0; j < 7; ++j) {
        float s = v[j];
        float q = v[j] * v[j];
        for (int off = 32; off > 0; off >>= 1) {
            s += __shfl_down(s, off);
            q += __shfl_down(q, off);
        }
        if (lane == 0) {
            atomicAdd(&ls[j], s);
            atomicAdd(&ls[8 + j], q);
        }
    }
    __syncthreads();
    if (t < 8)               atomicAdd(&colsum[t], ls[t]);
    else if (t < 16)         atomicAdd(&colsq[t - 8], ls[t]);
}

// ---------------- layer-1 gather: G = S . xp (L2-resident 16B rows) ----------------

__global__ void k_gather8(const __half* __restrict__ xp, const int* __restrict__ csr_s,
                          const float* __restrict__ csr_w,
                          const int* __restrict__ rs, const int* __restrict__ deg,
                          __half* __restrict__ out, float* __restrict__ rsum, int N) {
    int n = blockIdx.x * blockDim.x + threadIdx.x;
    if (n >= N) return;
    int e0 = rs[n], eend = e0 + deg[n];
    float a0 = 0.f, a1 = 0.f, a2 = 0.f, a3 = 0.f, a4 = 0.f, a5 = 0.f, a6 = 0.f, a7 = 0.f;
    float ws = 0.f;
    for (int e = e0; e < eend; ++e) {
        int s = csr_s[e];
        float w = csr_w[e];
        ws += w;
        float4 r = *(const float4*)(xp + (size_t)s * 8);
        const __half2* hh = (const __half2*)&r;
        float2 q0 = __half22float2(hh[0]);
        float2 q1 = __half22float2(hh[1]);
        float2 q2 = __half22float2(hh[2]);
        float2 q3 = __half22float2(hh[3]);
        a0 = fmaf(w, q0.x, a0); a1 = fmaf(w, q0.y, a1);
        a2 = fmaf(w, q1.x, a2); a3 = fmaf(w, q1.y, a3);
        a4 = fmaf(w, q2.x, a4); a5 = fmaf(w, q2.y, a5);
        a6 = fmaf(w, q3.x, a6); a7 = fmaf(w, q3.y, a7);
    }
    rsum[n] = ws;
    __half h[8];
    h[0] = __float2half(a0); h[1] = __float2half(a1);
    h[2] = __float2half(a2); h[3] = __float2half(a3);
    h[4] = __float2half(a4); h[5] = __float2half(a5);
    h[6] = __float2half(a6); h[7] = __float2half(a7);
    *(float4*)(out + (size_t)n * 8) = *(float4*)h;
}

// ------------- layer-1 MFMA GEMM (unchanged): split store + stats -------------

__global__ __launch_bounds__(256) void k_gemm_mfma(
    const f16* __restrict__ A, int SPa,
    const f16* __restrict__ Bt, int KP,
    const float* __restrict__ rsum, const float* __restrict__ wrow,
    const float* __restrict__ bias,
    f16* __restrict__ outM, int SPm, int MAIN, f16* __restrict__ outT, int TOTW,
    float* __restrict__ colsum, float* __restrict__ colsq, int do_stats,
    int N, int Cout) {
    __shared__ f16 As[128][40];
    __shared__ float s_sum[64];
    __shared__ float s_sq[64];
    const int r0 = blockIdx.x * 128;
    const int c0 = blockIdx.y * 64;
    const int t = threadIdx.x;
    const int wave = t >> 6, lane = t & 63;
    const int l15 = lane & 15, quad = lane >> 4;

    if (t < 64) { s_sum[t] = 0.f; s_sq[t] = 0.f; }

    f32x4 zero4 = {0.f, 0.f, 0.f, 0.f};
    f32x4 acc[2][4];
#pragma unroll
    for (int mi = 0; mi < 2; ++mi)
#pragma unroll
        for (int ni = 0; ni < 4; ++ni) acc[mi][ni] = zero4;

    const int KT = KP >> 5;
    for (int kt = 0; kt < KT; ++kt) {
        int k0 = kt * 32;
        {
            int kcol = (t & 7) * 4;
            int rbase = t >> 3;
            int gk = k0 + kcol;
            bool kok = (gk + 4 <= SPa);
#pragma unroll
            for (int i = 0; i < 4; ++i) {
                int row = rbase + i * 32;
                int gr = r0 + row;
                ushort4 v = {0, 0, 0, 0};
                if (gr < N && kok)
                    v = *(const ushort4*)(A + (size_t)gr * SPa + gk);
                *(ushort4*)&As[row][kcol] = v;
            }
        }
        __syncthreads();
        half8 a0 = *(const half8*)&As[wave * 32 + l15][quad * 8];
        half8 a1 = *(const half8*)&As[wave * 32 + 16 + l15][quad * 8];
#pragma unroll
        for (int ni = 0; ni < 4; ++ni) {
            half8 b = *(const half8*)(Bt + (size_t)(c0 + ni * 16 + l15) * KP + k0 + quad * 8);
            acc[0][ni] = __builtin_amdgcn_mfma_f32_16x16x32_f16(a0, b, acc[0][ni], 0, 0, 0);
            acc[1][ni] = __builtin_amdgcn_mfma_f32_16x16x32_f16(a1, b, acc[1][ni], 0, 0, 0);
        }
        __syncthreads();
    }

    float wr[4], bi[4];
#pragma unroll
    for (int ni = 0; ni < 4; ++ni) {
        int gc = c0 + ni * 16 + l15;
        wr[ni] = wrow[gc];
        bi[ni] = (gc < Cout) ? bias[gc] : 0.f;
    }
    float ps[4] = {}, pq[4] = {};
#pragma unroll
    for (int mi = 0; mi < 2; ++mi) {
#pragma unroll
        for (int reg = 0; reg < 4; ++reg) {
            int gr = r0 + wave * 32 + mi * 16 + quad * 4 + reg;
            if (gr >= N) continue;
            float rsv = rsum[gr];
#pragma unroll
            for (int ni = 0; ni < 4; ++ni) {
                int gc = c0 + ni * 16 + l15;
                float o = acc[mi][ni][reg] + rsv * wr[ni] + bi[ni];
                o = fmaxf(o, 0.f);
                if (gc >= Cout) o = 0.f;
                ps[ni] += o; pq[ni] += o * o;
                if (gc < MAIN) {
                    if (gc < TOTW) outM[(size_t)gr * SPm + gc] = (f16)o;
                } else if (gc < TOTW) {
                    outT[(size_t)gr * 8 + (gc - MAIN)] = (f16)o;
                }
            }
        }
    }
    if (do_stats) {
#pragma unroll
        for (int ni = 0; ni < 4; ++ni) {
            int cl = ni * 16 + l15;
            atomicAdd(&s_sum[cl], ps[ni]);
            atomicAdd(&s_sq[cl], pq[ni]);
        }
        __syncthreads();
        if (t < 64 && c0 + t < Cout) {
            atomicAdd(&colsum[c0 + t], s_sum[t]);
            atomicAdd(&colsq[c0 + t], s_sq[t]);
        }
    }
}

// helper: 8-half fma accumulate from a float4-of-halves
__device__ __forceinline__ void fma8(float* acc, float w, float4 r) {
    float2 q0 = __half22float2(((const __half2*)&r)[0]);
    float2 q1 = __half22float2(((const __half2*)&r)[1]);
    float2 q2 = __half22float2(((const __half2*)&r)[2]);
    float2 q3 = __half22float2(((const __half2*)&r)[3]);
    acc[0] = fmaf(w, q0.x, acc[0]); acc[1] = fmaf(w, q0.y, acc[1]);
    acc[2] = fmaf(w, q1.x, acc[2]); acc[3] = fmaf(w, q1.y, acc[3]);
    acc[4] = fmaf(w, q2.x, acc[4]); acc[5] = fmaf(w, q2.y, acc[5]);
    acc[6] = fmaf(w, q3.x, acc[6]); acc[7] = fmaf(w, q3.y, acc[7]);
}

// ==== fused layer-2: 64-row tile, gather(H1m/H1t)->LDS->GEMM(3 ct)->H2 + stats ====

__global__ __launch_bounds__(256) void k_fused2(
    const __half* __restrict__ Am, const __half* __restrict__ At,
    const f16* __restrict__ Bt,
    const int* __restrict__ rs, const int* __restrict__ deg,
    const int* __restrict__ csr_s, const float* __restrict__ csr_w,
    const float* __restrict__ rsum, const float* __restrict__ wrow,
    const float* __restrict__ bias,
    f16* __restrict__ outM, f16* __restrict__ outT,
    float* __restrict__ colsum, float* __restrict__ colsq, int N) {
    const int KP = 96, ASW = 104, SPM = 64, COUT = 135;
    __shared__ f16 As[64][104];
    __shared__ float s_red[4][64];
    __shared__ float s_red2[4][64];
    const int r0 = blockIdx.x * 64;
    const int t = threadIdx.x;
    const int wave = t >> 6, lane = t & 63;
    const int l15 = lane & 15, quad = lane >> 4;

    {   // zero As: covers K-pad cols [72,96) and rows >= N
        float4 z = {0.f, 0.f, 0.f, 0.f};
        for (int i = t; i < 64 * ASW / 8; i += 256) ((float4*)As)[i] = z;
    }
    __syncthreads();

    // ---- gather main (64 cols): 8 chunks x 8 nodes/pass, 2 passes/wave ----
    {
        const int sub = lane >> 3, lsub = lane & 7;
        const __half* gb = Am + lsub * 8;
        for (int pass = 0; pass < 2; ++pass) {
            int lrow = wave * 16 + pass * 8 + sub;
            int n = r0 + lrow;
            float acc[8] = {};
            if (n < N) {
                int e0 = rs[n], eend = e0 + deg[n];
                int e = e0;
                for (; e + 8 <= eend; e += 8) {
                    int s[8]; float wv[8]; float4 r[8];
#pragma unroll
                    for (int i = 0; i < 8; ++i) { s[i] = csr_s[e + i]; wv[i] = csr_w[e + i]; }
#pragma unroll
                    for (int i = 0; i < 8; ++i) r[i] = *(const float4*)(gb + (size_t)s[i] * SPM);
#pragma unroll
                    for (int i = 0; i < 8; ++i) fma8(acc, wv[i], r[i]);
                }
                for (; e + 4 <= eend; e += 4) {
                    int s[4]; float wv[4]; float4 r[4];
#pragma unroll
                    for (int i = 0; i < 4; ++i) { s[i] = csr_s[e + i]; wv[i] = csr_w[e + i]; }
#pragma unroll
                    for (int i = 0; i < 4; ++i) r[i] = *(const float4*)(gb + (size_t)s[i] * SPM);
#pragma unroll
                    for (int i = 0; i < 4; ++i) fma8(acc, wv[i], r[i]);
                }
                for (; e < eend; ++e)
                    fma8(acc, csr_w[e], *(const float4*)(gb + (size_t)csr_s[e] * SPM));
            }
            __half2 h[4];
            h[0] = __floats2half2_rn(acc[0], acc[1]);
            h[1] = __floats2half2_rn(acc[2], acc[3]);
            h[2] = __floats2half2_rn(acc[4], acc[5]);
            h[3] = __floats2half2_rn(acc[6], acc[7]);
            *(float4*)&As[lrow][lsub * 8] = *(float4*)h;
        }
    }
    // ---- gather tail (cols 64..72): 4 lanes/node over 16 nodes/wave ----
    {
        const int p = lane >> 2, sl = lane & 3;
        int lrow = wave * 16 + p;
        int n = r0 + lrow;
        float acc[8] = {};
        if (n < N) {
            int eend = rs[n] + deg[n];
            for (int e = rs[n] + sl; e < eend; e += 4)
                fma8(acc, csr_w[e], *(const float4*)(At + (size_t)csr_s[e] * 8));
        }
#pragma unroll
        for (int j = 0; j < 8; ++j) {
            acc[j] += __shfl_xor(acc[j], 1);
            acc[j] += __shfl_xor(acc[j], 2);
        }
        if (sl == 0) {
            __half2 h[4];
            h[0] = __floats2half2_rn(acc[0], acc[1]);
            h[1] = __floats2half2_rn(acc[2], acc[3]);
            h[2] = __floats2half2_rn(acc[4], acc[5]);
            h[3] = __floats2half2_rn(acc[6], acc[7]);
            *(float4*)&As[lrow][64] = *(float4*)h;
        }
    }
    __syncthreads();

    // ---- GEMM over 3 column tiles (As resident; gather done once) ----
    for (int ct = 0; ct < 3; ++ct) {
        const int c0 = ct * 64;
        f32x4 zero4 = {0.f, 0.f, 0.f, 0.f};
        f32x4 acc2[4];
#pragma unroll
        for (int ni = 0; ni < 4; ++ni) acc2[ni] = zero4;
#pragma unroll
        for (int kt = 0; kt < 3; ++kt) {
            int k0 = kt * 32;
            half8 a0 = *(const half8*)&As[wave * 16 + l15][k0 + quad * 8];
#pragma unroll
            for (int ni = 0; ni < 4; ++ni) {
                half8 b = *(const half8*)(Bt + (size_t)(c0 + ni * 16 + l15) * KP + k0 + quad * 8);
                acc2[ni] = __builtin_amdgcn_mfma_f32_16x16x32_f16(a0, b, acc2[ni], 0, 0, 0);
            }
        }
        float wr[4], bi[4];
#pragma unroll
        for (int ni = 0; ni < 4; ++ni) {
            int gc = c0 + ni * 16 + l15;
            wr[ni] = wrow[gc];
            bi[ni] = (gc < COUT) ? bias[gc] : 0.f;
        }
        float ps[4] = {}, pq[4] = {};
#pragma unroll
        for (int reg = 0; reg < 4; ++reg) {
            int gr = r0 + wave * 16 + quad * 4 + reg;
            if (gr >= N) continue;
            float rsv = rsum[gr];
#pragma unroll
            for (int ni = 0; ni < 4; ++ni) {
                int gc = c0 + ni * 16 + l15;
                float o = acc2[ni][reg] + rsv * wr[ni] + bi[ni];
                o = fmaxf(o, 0.f);
                if (gc >= COUT) o = 0.f;
                ps[ni] += o; pq[ni] += o * o;
                if (gc < 128)      outM[(size_t)gr * 128 + gc] = (f16)o;
                else if (gc < 136) outT[(size_t)gr * 8 + (gc - 128)] = (f16)o;
            }
        }
        // stats reduce: quad fold -> cross-wave LDS -> global atomics
#pragma unroll
        for (int ni = 0; ni < 4; ++ni) {
            ps[ni] += __shfl_down(ps[ni], 32); ps[ni] += __shfl_down(ps[ni], 16);
            pq[ni] += __shfl_down(pq[ni], 32); pq[ni] += __shfl_down(pq[ni], 16);
        }
        if (lane < 16) {
#pragma unroll
            for (int ni = 0; ni < 4; ++ni) {
                s_red[wave][ni * 16 + lane] = ps[ni];
                s_red2[wave][ni * 16 + lane] = pq[ni];
            }
        }
        __syncthreads();
        if (t < 64) {
            int gc = c0 + t;
            if (gc < COUT) {
                atomicAdd(&colsum[gc], s_red[0][t] + s_red[1][t] + s_red[2][t] + s_red[3][t]);
                atomicAdd(&colsq[gc], s_red2[0][t] + s_red2[1][t] + s_red2[2][t] + s_red2[3][t]);
            }
        }
        __syncthreads();
    }
}

// ==== fused layer-3: 64-row tile, gather(H2m/H2t)->LDS->GEMM(4 ct)->mean-pool ====

__global__ __launch_bounds__(256) void k_fused3(
    const __half* __restrict__ Am, const __half* __restrict__ At,
    const f16* __restrict__ Bt,
    const int* __restrict__ rs, const int* __restrict__ deg,
    const int* __restrict__ csr_s, const float* __restrict__ csr_w,
    const float* __restrict__ rsum, const float* __restrict__ wrow,
    const float* __restrict__ bias, const int* __restrict__ batch,
    float* __restrict__ pooled, int N) {
    const int KP = 160, ASW = 168, SPM = 128, COUT = 199;
    __shared__ f16 As[64][168];
    __shared__ int sbat[64];
    __shared__ float s_red[4][64];
    const int r0 = blockIdx.x * 64;
    const int t = threadIdx.x;
    const int wave = t >> 6, lane = t & 63;
    const int l15 = lane & 15, quad = lane >> 4;

    if (t < 64) {
        int gr = r0 + t;
        sbat[t] = batch[(gr < N) ? gr : (N - 1)];
    }
    {   // zero As: covers K-pad cols [136,160) and rows >= N
        float4 z = {0.f, 0.f, 0.f, 0.f};
        for (int i = t; i < 64 * ASW / 8; i += 256) ((float4*)As)[i] = z;
    }
    __syncthreads();

    // ---- gather main (128 cols): 16 chunks x 4 nodes/pass, 4 passes/wave ----
    {
        const int sub = lane >> 4, lsub = lane & 15;
        const __half* gb = Am + lsub * 8;
        for (int pass = 0; pass < 4; ++pass) {
            int lrow = wave * 16 + pass * 4 + sub;
            int n = r0 + lrow;
            float acc[8] = {};
            if (n < N) {
                int e0 = rs[n], eend = e0 + deg[n];
                int e = e0;
                for (; e + 8 <= eend; e += 8) {
                    int s[8]; float wv[8]; float4 r[8];
#pragma unroll
                    for (int i = 0; i < 8; ++i) { s[i] = csr_s[e + i]; wv[i] = csr_w[e + i]; }
#pragma unroll
                    for (int i = 0; i < 8; ++i) r[i] = *(const float4*)(gb + (size_t)s[i] * SPM);
#pragma unroll
                    for (int i = 0; i < 8; ++i) fma8(acc, wv[i], r[i]);
                }
                for (; e + 4 <= eend; e += 4) {
                    int s[4]; float wv[4]; float4 r[4];
#pragma unroll
                    for (int i = 0; i < 4; ++i) { s[i] = csr_s[e + i]; wv[i] = csr_w[e + i]; }
#pragma unroll
                    for (int i = 0; i < 4; ++i) r[i] = *(const float4*)(gb + (size_t)s[i] * SPM);
#pragma unroll
                    for (int i = 0; i < 4; ++i) fma8(acc, wv[i], r[i]);
                }
                for (; e < eend; ++e)
                    fma8(acc, csr_w[e], *(const float4*)(gb + (size_t)csr_s[e] * SPM));
            }
            __half2 h[4];
            h[0] = __floats2half2_rn(acc[0], acc[1]);
            h[1] = __floats2half2_rn(acc[2], acc[3]);
            h[2] = __floats2half2_rn(acc[4], acc[5]);
            h[3] = __floats2half2_rn(acc[6], acc[7]);
            *(float4*)&As[lrow][lsub * 8] = *(float4*)h;
        }
    }
    // ---- gather tail (cols 128..136): 4 lanes/node over 16 nodes/wave ----
    {
        const int p = lane >> 2, sl = lane & 3;
        int lrow = wave * 16 + p;
        int n = r0 + lrow;
        float acc[8] = {};
        if (n < N) {
            int eend = rs[n] + deg[n];
            for (int e = rs[n] + sl; e < eend; e += 4)
                fma8(acc, csr_w[e], *(const float4*)(At + (size_t)csr_s[e] * 8));
        }
#pragma unroll
        for (int j = 0; j < 8; ++j) {
            acc[j] += __shfl_xor(acc[j], 1);
            acc[j] += __shfl_xor(acc[j], 2);
        }
        if (sl == 0) {
            __half2 h[4];
            h[0] = __floats2half2_rn(acc[0], acc[1]);
            h[1] = __floats2half2_rn(acc[2], acc[3]);
            h[2] = __floats2half2_rn(acc[4], acc[5]);
            h[3] = __floats2half2_rn(acc[6], acc[7]);
            *(float4*)&As[lrow][128] = *(float4*)h;
        }
    }
    __syncthreads();

    // hoist per-thread row info (4 rows/thread)
    int gid[4]; float rsv4[4]; bool rok[4];
#pragma unroll
    for (int reg = 0; reg < 4; ++reg) {
        int lrow = wave * 16 + quad * 4 + reg;
        int gr = r0 + lrow;
        gid[reg] = sbat[lrow];
        rok[reg] = (gr < N);
        rsv4[reg] = rok[reg] ? rsum[gr] : 0.f;
    }
    const int g0 = sbat[0];
    const int gmax = sbat[63];

    // ---- GEMM over 4 column tiles + fused mean-pool ----
    for (int ct = 0; ct < 4; ++ct) {
        const int c0 = ct * 64;
        f32x4 zero4 = {0.f, 0.f, 0.f, 0.f};
        f32x4 acc2[4];
#pragma unroll
        for (int ni = 0; ni < 4; ++ni) acc2[ni] = zero4;
#pragma unroll
        for (int kt = 0; kt < 5; ++kt) {
            int k0 = kt * 32;
            half8 a0 = *(const half8*)&As[wave * 16 + l15][k0 + quad * 8];
#pragma unroll
            for (int ni = 0; ni < 4; ++ni) {
                half8 b = *(const half8*)(Bt + (size_t)(c0 + ni * 16 + l15) * KP + k0 + quad * 8);
                acc2[ni] = __builtin_amdgcn_mfma_f32_16x16x32_f16(a0, b, acc2[ni], 0, 0, 0);
            }
        }
        float wr[4], bi[4];
#pragma unroll
        for (int ni = 0; ni < 4; ++ni) {
            int gc = c0 + ni * 16 + l15;
            wr[ni] = wrow[gc];
            bi[ni] = (gc < COUT) ? bias[gc] : 0.f;
        }
        // relu epilogue in registers (invalid rows and cols forced to 0)
#pragma unroll
        for (int reg = 0; reg < 4; ++reg) {
#pragma unroll
            for (int ni = 0; ni < 4; ++ni) {
                int gc = c0 + ni * 16 + l15;
                float o = acc2[ni][reg] + rsv4[reg] * wr[ni] + bi[ni];
                o = fmaxf(o, 0.f);
                acc2[ni][reg] = (rok[reg] && gc < COUT) ? o : 0.f;
            }
        }
        // segmented pool: masked reg sum -> quad shuffle -> cross-wave LDS -> atomic
        for (int g = g0; g <= gmax; ++g) {
            float part[4] = {0.f, 0.f, 0.f, 0.f};
#pragma unroll
            for (int reg = 0; reg < 4; ++reg) {
                bool m = (gid[reg] == g);
#pragma unroll
                for (int ni = 0; ni < 4; ++ni)
                    part[ni] += m ? acc2[ni][reg] : 0.f;
            }
#pragma unroll
            for (int ni = 0; ni < 4; ++ni) {
                part[ni] += __shfl_down(part[ni], 32);
                part[ni] += __shfl_down(part[ni], 16);
            }
            if (lane < 16) {
#pragma unroll
                for (int ni = 0; ni < 4; ++ni) s_red[wave][ni * 16 + lane] = part[ni];
            }
            __syncthreads();
            if (t < 64) {
                int gc = c0 + t;
                if (gc < COUT) {
                    float v = s_red[0][t] + s_red[1][t] + s_red[2][t] + s_red[3][t];
                    if (v != 0.f) atomicAdd(&pooled[(size_t)g * COUT + gc], v);
                }
            }
            __syncthreads();
        }
    }
}

// ---------------- head MLP ----------------

__global__ void k_mlp(const float* __restrict__ pooled, const int* __restrict__ gstart,
                      const int* __restrict__ gend,
                      const float* __restrict__ Wl1, const float* __restrict__ bl1,
                      const float* __restrict__ Wl2, const float* __restrict__ bl2,
                      float* __restrict__ out, int C) {
    __shared__ float p[199];
    __shared__ float t1[49];
    int g = blockIdx.x;
    int cnt = gend[g] - gstart[g];
    float inv = 1.f / (float)(cnt > 1 ? cnt : 1);
    for (int k = threadIdx.x; k < C; k += blockDim.x) p[k] = pooled[g * C + k] * inv;
    __syncthreads();
    if (threadIdx.x < 49) {
        float acc = bl1[threadIdx.x];
        for (int k = 0; k < C; ++k) acc += p[k] * Wl1[k * 49 + threadIdx.x];
        t1[threadIdx.x] = acc;
    }
    __syncthreads();
    if (threadIdx.x < 2) {
        float acc = bl2[threadIdx.x];
        for (int k = 0; k < 49; ++k) acc += t1[k] * Wl2[k * 2 + threadIdx.x];
        out[g * 2 + threadIdx.x] = acc;
    }
}

// ---------------- launch ----------------

extern "C" void kernel_launch(void* const* d_in, const int* in_sizes, int n_in,
                              void* d_out, int out_size, void* d_ws, size_t ws_size,
                              hipStream_t stream) {
    const float* x     = (const float*)d_in[0];
    const int*   ei    = (const int*)d_in[1];
    const int*   batch = (const int*)d_in[2];
    const float* bn0g = (const float*)d_in[3];
    const float* bn0b = (const float*)d_in[4];
    const float* bn1g = (const float*)d_in[5];
    const float* bn1b = (const float*)d_in[6];
    const float* bn2g = (const float*)d_in[7];
    const float* bn2b = (const float*)d_in[8];
    const float* W1  = (const float*)d_in[9];
    const float* b1  = (const float*)d_in[10];
    const float* W2  = (const float*)d_in[11];
    const float* b2  = (const float*)d_in[12];
    const float* W3  = (const float*)d_in[13];
    const float* b3  = (const float*)d_in[14];
    const float* Wl1 = (const float*)d_in[15];
    const float* bl1 = (const float*)d_in[16];
    const float* Wl2 = (const float*)d_in[17];
    const float* bl2 = (const float*)d_in[18];

    const int N = in_sizes[0] / 7;
    const int E = in_sizes[1] / 2;
    const int EN = E + N;
    const int G = out_size / 2;
    const int NB = (N + 255) / 256;
    const int NBK = (N + 255) / 256;        // buckets of 256 nodes
    const int NBIN = (EN + BIN_CH - 1) / BIN_CH;

    const int* src = ei;
    const int* dst = ei + E;

    char* w = (char*)d_ws;
    auto alloc = [&](size_t bytes) -> void* {
        void* p = (void*)w;
        w += ((bytes + 255) / 256) * 256;
        return p;
    };
    // Split H-tables:
    //   H1m [N,64]h | H1t [N,8]h | H2m [N,128]h | H2t [N,8]h
    size_t szH1m = (size_t)N * 64 * sizeof(__half);
    size_t szH1t = (size_t)N * 8 * sizeof(__half);
    size_t szH2m = (size_t)N * 128 * sizeof(__half);
    size_t szH2t = (size_t)N * 8 * sizeof(__half);
    char* regA = (char*)alloc(szH1m + szH1t + szH2m + szH2t);
    __half* H1m = (__half*)regA;
    __half* H1t = (__half*)(regA + szH1m);
    __half* H2m = (__half*)(regA + szH1m + szH1t);
    __half* H2t = (__half*)(regA + szH1m + szH1t + szH2m);

    __half* bufG = (__half*)alloc((size_t)N * 8 * sizeof(__half));   // layer-1 gather output
    f16*    wp   = (f16*)  alloc((size_t)256 * 160 * sizeof(f16));
    float*  wrow = (float*)alloc(256 * sizeof(float));
    __half* xp   = (__half*)alloc((size_t)N * 8 * sizeof(__half));
    float* disq  = (float*)alloc((size_t)N * sizeof(float));
    float* rsum  = (float*)alloc((size_t)N * sizeof(float));
    int*   deg   = (int*)  alloc((size_t)N * sizeof(int));
    int*   rs    = (int*)  alloc((size_t)N * sizeof(int));
    int*   binned= (int*)  alloc((size_t)NBK * BCAP * sizeof(int));
    int*   csr_s = (int*)  alloc((size_t)NBK * BCAP * sizeof(int));
    float* csr_w = (float*)alloc((size_t)NBK * BCAP * sizeof(float));
    // contiguous zero-init region: 6 stat arrays (1KB each) + gcur (2KB) + pooled
    float* colsum0 = (float*)alloc(256 * sizeof(float));
    float* colsq0  = (float*)alloc(256 * sizeof(float));
    float* colsumA = (float*)alloc(256 * sizeof(float));
    float* colsqA  = (float*)alloc(256 * sizeof(float));
    float* colsumB = (float*)alloc(256 * sizeof(float));
    float* colsqB  = (float*)alloc(256 * sizeof(float));
    int*   gcur    = (int*)  alloc(512 * sizeof(int));
    float* pooled  = (float*)alloc((size_t)G * 199 * sizeof(float));
    int*   gstart  = (int*)  alloc((size_t)G * sizeof(int));
    int*   gend    = (int*)  alloc((size_t)G * sizeof(int));

    size_t zbytes = 6 * 1024 + 2048 + (((size_t)G * 199 * sizeof(float) + 255) / 256) * 256;
    hipMemsetAsync(colsum0, 0, zbytes, stream);   // stats + gcur + pooled, one node

    // ---- binned CSR build (single pass, fixed-capacity buckets) ----
    k_bin<<<NBIN, 256, 0, stream>>>(src, dst, E, EN, NBK, gcur, binned);
    k_bucket<<<NBK, 256, 0, stream>>>(binned, gcur, N, deg, rs, csr_s, disq);
    k_wfill<<<(N + 3) / 4, 256, 0, stream>>>(rs, deg, csr_s, disq, csr_w, N);

    const int GB = (N + 127) / 128;
    const int GB64 = (N + 63) / 64;

    // ---- layer 1 ----
    k_padx_stats<<<NB, 256, 0, stream>>>(x, xp, N, colsum0, colsq0, batch, gstart, gend);
    k_prep<<<128, 256, 0, stream>>>(colsum0, colsq0, bn0g, bn0b, 1.f / (float)N,
                                    W1, 7, 71, 32, wp, wrow);
    k_gather8<<<(N + 255) / 256, 256, 0, stream>>>(xp, csr_s, csr_w, rs, deg, bufG, rsum, N);
    {
        dim3 grid(GB, 2);
        k_gemm_mfma<<<grid, 256, 0, stream>>>((const f16*)bufG, 8, wp, 32, rsum, wrow, b1,
                                              (f16*)H1m, 64, 64, (f16*)H1t, 72,
                                              colsumA, colsqA, 1, N, 71);
    }
    // ---- layer 2 (fused gather+GEMM; 64-row tiles) ----
    k_prep<<<192, 256, 0, stream>>>(colsumA, colsqA, bn1g, bn1b, 1.f / (float)N,
                                    W2, 71, 135, 96, wp, wrow);
    k_fused2<<<GB64, 256, 0, stream>>>(H1m, H1t, wp, rs, deg, csr_s, csr_w,
                                       rsum, wrow, b2, (f16*)H2m, (f16*)H2t,
                                       colsumB, colsqB, N);
    // ---- layer 3 (fused gather+GEMM+mean-pool; 64-row tiles) ----
    k_prep<<<256, 256, 0, stream>>>(colsumB, colsqB, bn2g, bn2b, 1.f / (float)N,
                                    W3, 135, 199, 160, wp, wrow);
    k_fused3<<<GB64, 256, 0, stream>>>(H2m, H2t, wp, rs, deg, csr_s, csr_w,
                                       rsum, wrow, b3, batch, pooled, N);

    // ---- head ----
    k_mlp<<<G, 64, 0, stream>>>(pooled, gstart, gend, Wl1, bl1, Wl2, bl2, (float*)d_out, 199);
}